// Round 4
// baseline (2599.176 us; speedup 1.0000x reference)
//
#include <hip/hip_runtime.h>
#include <hip/hip_bf16.h>
#include <cstddef>

#define BATCH  4
#define SEQL   4096
#define DM     512
#define DIP    2192
#define DIPP   2304
#define DI     1024
#define DST    64
#define NH     16
#define HD     64
#define CONVD  1152
#define NROWS  (BATCH*SEQL)

typedef __attribute__((ext_vector_type(8))) short short8;
typedef __attribute__((ext_vector_type(4))) float f32x4;

__device__ __forceinline__ float silu_f(float v){ return v/(1.f+__expf(-v)); }

__device__ __forceinline__ unsigned short bf16_rne(float x){
  unsigned u = __float_as_uint(x);
  unsigned r = u + 0x7FFFu + ((u>>16)&1u);
  return (unsigned short)(r>>16);
}
__device__ __forceinline__ float bf16_to_f(unsigned short h){
  return __uint_as_float(((unsigned)h)<<16);
}

// ---------------- per-row LN stats ----------------
__global__ __launch_bounds__(256)
void k_stats(const float* __restrict__ x, float* __restrict__ stats){
  __shared__ float sm[8];
  int row = blockIdx.x, t = threadIdx.x;
  const float* xr = x + (size_t)row*DM;
  float v0 = xr[t], v1 = xr[t+256];
  float s = v0+v1, s2 = v0*v0+v1*v1;
  for(int o=32;o;o>>=1){ s += __shfl_down(s,o); s2 += __shfl_down(s2,o); }
  if((t&63)==0){ sm[t>>6]=s; sm[4+(t>>6)]=s2; }
  __syncthreads();
  if(t==0){
    float su = sm[0]+sm[1]+sm[2]+sm[3];
    float sq = sm[4]+sm[5]+sm[6]+sm[7];
    float mu = su*(1.f/DM);
    float rs = rsqrtf(sq*(1.f/DM) - mu*mu + 1e-5f);
    stats[row*2] = mu; stats[row*2+1] = rs;
  }
}

// ------- transpose + split fp32[K][N] -> bf16 hi/lo [Npad][K]; pad rows zeroed -------
__global__ void k_wsplit(const float* __restrict__ src, unsigned short* __restrict__ dh,
                         unsigned short* __restrict__ dl, int K, int N){
  __shared__ float sm[32][33];
  int tx = threadIdx.x, ty = threadIdx.y;     // (32,8)
  int n0 = blockIdx.x*32, k0 = blockIdx.y*32;
  #pragma unroll
  for(int j=0;j<4;j++){
    int k = k0+ty+j*8, n = n0+tx;
    sm[ty+j*8][tx] = (k<K && n<N) ? src[(size_t)k*N+n] : 0.f;
  }
  __syncthreads();
  #pragma unroll
  for(int j=0;j<4;j++){
    int n = n0+ty+j*8, k = k0+tx;
    float v = sm[tx][ty+j*8];
    unsigned short hh = bf16_rne(v);
    dh[(size_t)n*K+k] = hh;
    dl[(size_t)n*K+k] = bf16_rne(v - bf16_to_f(hh));
  }
}

// ---- in_proj GEMM: LN(x) @ in_w, split-bf16 3-MFMA, epilogue scatters z/xbc ----
__global__ __launch_bounds__(256)
void k_gemm_in(const float* __restrict__ x, const float* __restrict__ stats,
               const float* __restrict__ lnw, const float* __restrict__ lnb,
               const unsigned short* __restrict__ Bhg, const unsigned short* __restrict__ Blg,
               float* __restrict__ z, float* __restrict__ xbc){
  __shared__ unsigned short Ah[128][72], Al[128][72], Bh[128][72], Bl[128][72];
  const int ntn = DIPP/128;                    // 18
  int bid = blockIdx.x;
  int tm = bid / ntn, tn = bid % ntn;
  int t = threadIdx.x, lane = t&63, wave = t>>6;
  int wr = (wave>>1)*64, wc = (wave&1)*64, fr = lane&15;
  f32x4 zero = {0.f,0.f,0.f,0.f};
  f32x4 acc[4][4];
  #pragma unroll
  for(int m=0;m<4;m++)
    #pragma unroll
    for(int n=0;n<4;n++) acc[m][n]=zero;
  const int arow = tm*128, bcol = tn*128;
  for(int k0=0; k0<DM; k0+=64){
    __syncthreads();
    #pragma unroll
    for(int i=0;i<8;i++){
      int idx = t + i*256;
      int r = idx>>4, cq = (idx&15)*4;
      int grow = arow + r;
      f32x4 xv = *(const f32x4*)(x + (size_t)grow*DM + k0 + cq);
      float mu = stats[grow*2], rsd = stats[grow*2+1];
      f32x4 wv = *(const f32x4*)(lnw + k0 + cq);
      f32x4 bv = *(const f32x4*)(lnb + k0 + cq);
      #pragma unroll
      for(int j=0;j<4;j++){
        float v = (xv[j]-mu)*rsd*wv[j] + bv[j];
        unsigned short hh = bf16_rne(v);
        Ah[r][cq+j] = hh;
        Al[r][cq+j] = bf16_rne(v - bf16_to_f(hh));
      }
    }
    #pragma unroll
    for(int i=0;i<4;i++){
      int idx = t + i*256;
      int r = idx>>3, c8 = (idx&7)*8;
      *(short8*)(&Bh[r][c8]) = *(const short8*)(Bhg + (size_t)(bcol+r)*DM + k0 + c8);
      *(short8*)(&Bl[r][c8]) = *(const short8*)(Blg + (size_t)(bcol+r)*DM + k0 + c8);
    }
    __syncthreads();
    #pragma unroll
    for(int kk=0;kk<2;kk++){
      int fk = kk*32 + ((lane>>4)<<3);
      short8 afh[4], afl[4], bfh[4], bfl[4];
      #pragma unroll
      for(int m=0;m<4;m++){
        afh[m] = *(const short8*)(&Ah[wr+m*16+fr][fk]);
        afl[m] = *(const short8*)(&Al[wr+m*16+fr][fk]);
      }
      #pragma unroll
      for(int n=0;n<4;n++){
        bfh[n] = *(const short8*)(&Bh[wc+n*16+fr][fk]);
        bfl[n] = *(const short8*)(&Bl[wc+n*16+fr][fk]);
      }
      #pragma unroll
      for(int m=0;m<4;m++)
        #pragma unroll
        for(int n=0;n<4;n++){
          acc[m][n] = __builtin_amdgcn_mfma_f32_16x16x32_bf16(afh[m], bfh[n], acc[m][n], 0,0,0);
          acc[m][n] = __builtin_amdgcn_mfma_f32_16x16x32_bf16(afh[m], bfl[n], acc[m][n], 0,0,0);
          acc[m][n] = __builtin_amdgcn_mfma_f32_16x16x32_bf16(afl[m], bfh[n], acc[m][n], 0,0,0);
        }
    }
  }
  int fq = (lane>>4)*4;
  #pragma unroll
  for(int m=0;m<4;m++)
    #pragma unroll
    for(int n=0;n<4;n++)
      #pragma unroll
      for(int j=0;j<4;j++){
        int row = arow + wr + m*16 + fq + j;
        int col = bcol + wc + n*16 + fr;
        float v = acc[m][n][j];
        if(col < DI) z[(size_t)row*DI + col] = v;
        else if(col < DI+CONVD) xbc[(size_t)row*CONVD + (col-DI)] = v;
        // cols >= 2176: dt handled exactly by k_dt; pad cols dropped
      }
}

// ---- out_proj GEMM: g(Sreg scattered) @ out_w + x -> out ----
__global__ __launch_bounds__(256)
void k_gemm_out(const float* __restrict__ G, const unsigned short* __restrict__ Bhg,
                const unsigned short* __restrict__ Blg, const float* __restrict__ resid,
                float* __restrict__ outp){
  __shared__ unsigned short Ah[128][72], Al[128][72], Bh[128][72], Bl[128][72];
  const int ntn = DM/128;                      // 4
  int bid = blockIdx.x;
  int tm = bid / ntn, tn = bid % ntn;
  int t = threadIdx.x, lane = t&63, wave = t>>6;
  int wr = (wave>>1)*64, wc = (wave&1)*64, fr = lane&15;
  f32x4 zero = {0.f,0.f,0.f,0.f};
  f32x4 acc[4][4];
  #pragma unroll
  for(int m=0;m<4;m++)
    #pragma unroll
    for(int n=0;n<4;n++) acc[m][n]=zero;
  const int arow = tm*128, bcol = tn*128;
  for(int k0=0; k0<DI; k0+=64){
    __syncthreads();
    int h = k0>>6;
    #pragma unroll
    for(int i=0;i<8;i++){
      int idx = t + i*256;
      int r = idx>>4, cq = (idx&15)*4;
      int grow = arow + r;
      int bb = grow>>12, cc = (grow>>6)&63, lin = grow&63;
      size_t base = ((size_t)((bb*64+cc)*NH + h))*4096 + (size_t)lin*64;
      f32x4 gv = *(const f32x4*)(G + base + cq);
      #pragma unroll
      for(int j=0;j<4;j++){
        unsigned short hh = bf16_rne(gv[j]);
        Ah[r][cq+j] = hh;
        Al[r][cq+j] = bf16_rne(gv[j] - bf16_to_f(hh));
      }
    }
    #pragma unroll
    for(int i=0;i<4;i++){
      int idx = t + i*256;
      int r = idx>>3, c8 = (idx&7)*8;
      *(short8*)(&Bh[r][c8]) = *(const short8*)(Bhg + (size_t)(bcol+r)*DI + k0 + c8);
      *(short8*)(&Bl[r][c8]) = *(const short8*)(Blg + (size_t)(bcol+r)*DI + k0 + c8);
    }
    __syncthreads();
    #pragma unroll
    for(int kk=0;kk<2;kk++){
      int fk = kk*32 + ((lane>>4)<<3);
      short8 afh[4], afl[4], bfh[4], bfl[4];
      #pragma unroll
      for(int m=0;m<4;m++){
        afh[m] = *(const short8*)(&Ah[wr+m*16+fr][fk]);
        afl[m] = *(const short8*)(&Al[wr+m*16+fr][fk]);
      }
      #pragma unroll
      for(int n=0;n<4;n++){
        bfh[n] = *(const short8*)(&Bh[wc+n*16+fr][fk]);
        bfl[n] = *(const short8*)(&Bl[wc+n*16+fr][fk]);
      }
      #pragma unroll
      for(int m=0;m<4;m++)
        #pragma unroll
        for(int n=0;n<4;n++){
          acc[m][n] = __builtin_amdgcn_mfma_f32_16x16x32_bf16(afh[m], bfh[n], acc[m][n], 0,0,0);
          acc[m][n] = __builtin_amdgcn_mfma_f32_16x16x32_bf16(afh[m], bfl[n], acc[m][n], 0,0,0);
          acc[m][n] = __builtin_amdgcn_mfma_f32_16x16x32_bf16(afl[m], bfh[n], acc[m][n], 0,0,0);
        }
    }
  }
  int fq = (lane>>4)*4;
  #pragma unroll
  for(int m=0;m<4;m++)
    #pragma unroll
    for(int n=0;n<4;n++)
      #pragma unroll
      for(int j=0;j<4;j++){
        int row = arow + wr + m*16 + fq + j;
        int col = bcol + wc + n*16 + fr;
        outp[(size_t)row*DM + col] = acc[m][n][j] + resid[(size_t)row*DM + col];
      }
}

// ---------------- exact fp32 dt ----------------
__global__ __launch_bounds__(256)
void k_dt(const float* __restrict__ x, const float* __restrict__ stats,
          const float* __restrict__ lnw, const float* __restrict__ lnb,
          const float* __restrict__ in_w, const float* __restrict__ dt_bias,
          float* __restrict__ dtp){
  __shared__ float red[64];
  int row = blockIdx.x, t = threadIdx.x;
  float mu = stats[row*2], rs = stats[row*2+1];
  float a[16];
  #pragma unroll
  for(int j=0;j<16;j++) a[j]=0.f;
  #pragma unroll
  for(int i=0;i<2;i++){
    int k = t + i*256;
    float hv = (x[(size_t)row*DM + k]-mu)*rs*lnw[k] + lnb[k];
    const float* wr2 = in_w + (size_t)k*DIP + (DIP-NH);
    #pragma unroll
    for(int j=0;j<16;j++) a[j] += hv * wr2[j];
  }
  for(int o=32;o;o>>=1){
    #pragma unroll
    for(int j=0;j<16;j++) a[j] += __shfl_down(a[j],o);
  }
  if((t&63)==0){
    #pragma unroll
    for(int j=0;j<16;j++) red[(t>>6)*16+j] = a[j];
  }
  __syncthreads();
  if(t<16){
    float v = red[t] + red[16+t] + red[32+t] + red[48+t] + dt_bias[t];
    dtp[(size_t)row*NH + t] = (v > 20.f) ? v : log1pf(__expf(v));
  }
}

// ---------------- conv+silu for B/C channels only -> bcc[row][128] ----------------
__global__ __launch_bounds__(256)
void k_convBC(const float* __restrict__ xbc, const float* __restrict__ cw,
              const float* __restrict__ cb, float* __restrict__ bcc){
  int gid = blockIdx.x*256 + threadIdx.x;     // NROWS*32
  int c4 = gid & 31, row = gid >> 5;
  int c = c4*4;                                // channel 1024+c .. +3
  int lb = row & (SEQL-1);
  const float* base = xbc + (size_t)row*CONVD + DI + c;
  f32x4 w0 = *(const f32x4*)(cw + (size_t)(DI+c+0)*4);
  f32x4 w1 = *(const f32x4*)(cw + (size_t)(DI+c+1)*4);
  f32x4 w2 = *(const f32x4*)(cw + (size_t)(DI+c+2)*4);
  f32x4 w3 = *(const f32x4*)(cw + (size_t)(DI+c+3)*4);
  f32x4 r = { cb[DI+c], cb[DI+c+1], cb[DI+c+2], cb[DI+c+3] };
  #pragma unroll
  for(int k=0;k<4;k++){
    if(lb-3+k >= 0){
      f32x4 xv = *(const f32x4*)(base + (long)(k-3)*CONVD);
      r.x += xv.x*w0[k]; r.y += xv.y*w1[k]; r.z += xv.z*w2[k]; r.w += xv.w*w3[k];
    }
  }
  r.x = silu_f(r.x); r.y = silu_f(r.y); r.z = silu_f(r.z); r.w = silu_f(r.w);
  *(f32x4*)(bcc + (size_t)row*128 + c) = r;
}

// ---------------- per-chunk cumsum of dt*A ----------------
__global__ void k_acum(const float* __restrict__ dtp, const float* __restrict__ A_log,
                       float* __restrict__ acum, float* __restrict__ cdec){
  int bh = blockIdx.x;                 // b*16+h
  int h = bh & 15;
  int c = blockIdx.y, l = threadIdx.x; // 64 threads
  int row = (bh>>4)*SEQL + c*64 + l;
  float a = -__expf(A_log[h]);
  float v = dtp[(size_t)row*NH + h] * a;
  for(int o=1;o<64;o<<=1){ float u = __shfl_up(v,o); if(l>=o) v += u; }
  acum[(size_t)bh*SEQL + c*64 + l] = v;
  if(l==63) cdec[bh*64 + c] = __expf(v);
}

// ---------------- Phase A: chunk states (conv-recompute for x-head) ----------------
__global__ __launch_bounds__(256)
void k_states(const float* __restrict__ xbc, const float* __restrict__ bcc,
              const float* __restrict__ dtp, const float* __restrict__ acum,
              const float* __restrict__ cw, const float* __restrict__ cb,
              float* __restrict__ S){
  int b = blockIdx.x >> 6, c = blockIdx.x & 63, h = blockIdx.y;
  __shared__ float Bd[64][68];
  __shared__ float Xs[64][68];
  __shared__ float raw[67*64];
  __shared__ f32x4 wc4[64];
  __shared__ float cbv[64], acs[64], dts[64];
  int t = threadIdx.x;
  if(t < 64){
    acs[t] = acum[((size_t)(b*NH+h))*SEQL + c*64 + t];
    dts[t] = dtp[(size_t)(b*SEQL + c*64 + t)*NH + h];
    wc4[t] = *(const f32x4*)(cw + (size_t)(h*HD + t)*4);
    cbv[t] = cb[h*HD + t];
  }
  __syncthreads();
  #pragma unroll
  for(int i=0;i<4;i++){
    int idx = t + i*256;
    int l = idx>>4, n4 = (idx&15)*4;
    f32x4 bv = *(const f32x4*)(bcc + (size_t)(b*SEQL + c*64 + l)*128 + n4);
    float dec = __expf(acs[63] - acs[l]);
    *(f32x4*)&Bd[l][n4] = bv * dec;
  }
  #pragma unroll
  for(int i=0;i<5;i++){
    int idx = t + i*256;
    if(idx < 67*16){
      int rr = idx>>4, p4 = (idx&15)*4;
      int wb = c*64 - 3 + rr;
      f32x4 xv = {0.f,0.f,0.f,0.f};
      if(wb >= 0) xv = *(const f32x4*)(xbc + (size_t)(b*SEQL + wb)*CONVD + h*HD + p4);
      *(f32x4*)&raw[rr*64 + p4] = xv;
    }
  }
  __syncthreads();
  {
    int l = t>>2, q = t&3;
    float dtv = dts[l];
    #pragma unroll
    for(int jj=0;jj<16;jj++){
      int p = q*16 + jj;
      f32x4 w = wc4[p];
      float a = cbv[p] + raw[(l+0)*64+p]*w.x + raw[(l+1)*64+p]*w.y
              + raw[(l+2)*64+p]*w.z + raw[(l+3)*64+p]*w.w;
      Xs[l][p] = silu_f(a) * dtv;
    }
  }
  __syncthreads();
  int n = t>>2, p0 = (t&3)*16;
  f32x4 a0={0.f,0.f,0.f,0.f}, a1=a0, a2=a0, a3=a0;
  for(int ll=0; ll<64; ll++){
    float bnd = Bd[ll][n];
    const float* xp = &Xs[ll][p0];
    a0 += bnd * *(const f32x4*)(xp);
    a1 += bnd * *(const f32x4*)(xp+4);
    a2 += bnd * *(const f32x4*)(xp+8);
    a3 += bnd * *(const f32x4*)(xp+12);
  }
  float* op = S + ((size_t)((b*64+c)*NH + h))*4096 + n*64 + p0;
  *(f32x4*)(op)    = a0;
  *(f32x4*)(op+4)  = a1;
  *(f32x4*)(op+8)  = a2;
  *(f32x4*)(op+12) = a3;
}

// ---------------- Phase B: inter-chunk scan (prev in-place) ----------------
__global__ void k_scan(float* __restrict__ S, const float* __restrict__ cdec){
  int g = blockIdx.x*256 + threadIdx.x;  // BATCH*NH*4096
  int bh = g >> 12;
  int pn = g & 4095;
  int b = bh >> 4, h = bh & 15;
  const float* cd = cdec + bh*64;
  float s = 0.f;
  for(int c=0;c<64;c++){
    size_t idx = ((size_t)((b*64 + c)*NH + h))*4096 + pn;
    float v = S[idx];
    float d = cd[c];
    S[idx] = s;
    s = s*d + v;
  }
}

// ---------------- Phase C: Y written in-place over prev slot ----------------
// Strict phase separation to keep live VGPRs low (r3: 256 VGPR + 2.5GB scratch spill
// made this kernel 1.3ms; no phase here needs >~90 live regs).
__global__ __launch_bounds__(256, 2)
void k_y(const float* __restrict__ xbc, const float* __restrict__ bcc,
         const float* __restrict__ dtp, const float* __restrict__ acum,
         const float* __restrict__ cw, const float* __restrict__ cb,
         const float* __restrict__ Dp, float* __restrict__ Sreg){
  int b = blockIdx.x >> 6, c = blockIdx.x & 63, h = blockIdx.y;
  __shared__ float Cs[64][68];
  __shared__ float BM[64][68];         // B, then overwritten with M
  __shared__ float Xr[64][68];
  __shared__ float PsRaw[64*68];       // raw x [67*64], then Ps [s*68+p]
  __shared__ f32x4 wc4[64];
  __shared__ float cbv[64], acs[64], dts[64];
  int t = threadIdx.x;
  float* Sslot = Sreg + ((size_t)((b*64+c)*NH + h))*4096;
  // ---- phase 1: stage B, C, raw x, scalars ----
  if(t < 64){
    acs[t] = acum[((size_t)(b*NH+h))*SEQL + c*64 + t];
    dts[t] = dtp[(size_t)(b*SEQL + c*64 + t)*NH + h];
    wc4[t] = *(const f32x4*)(cw + (size_t)(h*HD + t)*4);
    cbv[t] = cb[h*HD + t];
  }
  #pragma unroll
  for(int i=0;i<4;i++){
    int idx = t + i*256;
    int l = idx>>4, n4 = (idx&15)*4;
    const float* bp = bcc + (size_t)(b*SEQL + c*64 + l)*128;
    *(f32x4*)&BM[l][n4] = *(const f32x4*)(bp + n4);       // B
    *(f32x4*)&Cs[l][n4] = *(const f32x4*)(bp + 64 + n4);  // C
  }
  #pragma unroll
  for(int i=0;i<5;i++){
    int idx = t + i*256;
    if(idx < 67*16){
      int rr = idx>>4, p4 = (idx&15)*4;
      int wb = c*64 - 3 + rr;
      f32x4 xv = {0.f,0.f,0.f,0.f};
      if(wb >= 0) xv = *(const f32x4*)(xbc + (size_t)(b*SEQL + wb)*CONVD + h*HD + p4);
      *(f32x4*)&PsRaw[rr*64 + p4] = xv;
    }
  }
  __syncthreads();
  // ---- phase 2: conv + silu -> Xr ----
  {
    int l = t>>2, q = t&3;
    #pragma unroll
    for(int jj=0;jj<16;jj++){
      int p = q*16 + jj;
      f32x4 w = wc4[p];
      float a = cbv[p] + PsRaw[(l+0)*64+p]*w.x + PsRaw[(l+1)*64+p]*w.y
              + PsRaw[(l+2)*64+p]*w.z + PsRaw[(l+3)*64+p]*w.w;
      Xr[l][p] = silu_f(a);
    }
  }
  __syncthreads();
  // ---- phase 3: G[l][s] = sum_n C[l][n]*B[s][n] (registers g[16] only) ----
  int gl = t & 63, s0 = (t>>6)*16;
  float g[16];
  #pragma unroll
  for(int j=0;j<16;j++) g[j]=0.f;
  for(int n4=0;n4<64;n4+=4){
    f32x4 cv = *(const f32x4*)&Cs[gl][n4];
    #pragma unroll
    for(int j=0;j<16;j++){
      f32x4 bv = *(const f32x4*)&BM[s0+j][n4];
      g[j] += cv.x*bv.x + cv.y*bv.y + cv.z*bv.z + cv.w*bv.w;
    }
  }
  __syncthreads();   // all G reads of BM done before M overwrite
  // ---- phase 4: M over BM, and stage Ps over raw (conv done, G done) ----
  {
    float aclg = acs[gl];
    #pragma unroll
    for(int j=0;j<16;j++){
      int s = s0 + j;
      BM[gl][s] = (s <= gl) ? g[j]*__expf(aclg - acs[s])*dts[s] : 0.f;
    }
  }
  #pragma unroll
  for(int i=0;i<4;i++){
    int idx = t + i*256;
    int s = idx>>4, p4 = (idx&15)*4;
    f32x4 pv = *(const f32x4*)(Sslot + s*64 + p4);
    *(f32x4*)&PsRaw[s*68 + p4] = pv;
  }
  __syncthreads();
  // ---- phase 5: Y[l][p] = sum_s M[l][s]*Xr[s][p] + exp(ac[l])*sum_s C[l][s]*Ps[s][p] + D*Xr[l][p]
  int l = t>>2, p0 = (t&3)*16;
  float eal = __expf(acs[l]);
  float Dh = Dp[h];
  f32x4 z4 = {0.f,0.f,0.f,0.f};
  f32x4 yd0=z4, yd1=z4, yd2=z4, yd3=z4;
  f32x4 yo0=z4, yo1=z4, yo2=z4, yo3=z4;
  for(int s=0;s<64;s++){
    float m = BM[l][s];
    const float* xp = &Xr[s][p0];
    yd0 += m * *(const f32x4*)(xp);
    yd1 += m * *(const f32x4*)(xp+4);
    yd2 += m * *(const f32x4*)(xp+8);
    yd3 += m * *(const f32x4*)(xp+12);
    float cv = Cs[l][s];
    const float* pp = &PsRaw[s*68 + p0];
    yo0 += cv * *(const f32x4*)(pp);
    yo1 += cv * *(const f32x4*)(pp+4);
    yo2 += cv * *(const f32x4*)(pp+8);
    yo3 += cv * *(const f32x4*)(pp+12);
  }
  const float* xl = &Xr[l][p0];
  f32x4 r0 = yd0 + eal*yo0 + Dh * *(const f32x4*)(xl);
  f32x4 r1 = yd1 + eal*yo1 + Dh * *(const f32x4*)(xl+4);
  f32x4 r2 = yd2 + eal*yo2 + Dh * *(const f32x4*)(xl+8);
  f32x4 r3 = yd3 + eal*yo3 + Dh * *(const f32x4*)(xl+12);
  float* yp = Sslot + l*64 + p0;     // in-place over prev (staged to LDS already)
  *(f32x4*)(yp)    = r0;
  *(f32x4*)(yp+4)  = r1;
  *(f32x4*)(yp+8)  = r2;
  *(f32x4*)(yp+12) = r3;
}

// ---------------- gate + RMSNorm, in-place over y (scattered layout) ----------------
__global__ __launch_bounds__(256)
void k_gate(float* __restrict__ Sreg, const float* __restrict__ z,
            const float* __restrict__ rms_w){
  __shared__ float sm[4];
  int row = blockIdx.x, t = threadIdx.x;
  int b = row>>12, cc = (row>>6)&63, lin = row&63;
  int h = t>>4, p = (t&15)*4;
  float* gp = Sreg + ((size_t)((b*64+cc)*NH + h))*4096 + (size_t)lin*64 + p;
  f32x4 yv = *(const f32x4*)gp;
  f32x4 zv = *(const f32x4*)(z + (size_t)row*DI + t*4);
  f32x4 gv;
  gv.x = yv.x * silu_f(zv.x);
  gv.y = yv.y * silu_f(zv.y);
  gv.z = yv.z * silu_f(zv.z);
  gv.w = yv.w * silu_f(zv.w);
  float ss = gv.x*gv.x + gv.y*gv.y + gv.z*gv.z + gv.w*gv.w;
  for(int o=32;o;o>>=1) ss += __shfl_down(ss,o);
  if((t&63)==0) sm[t>>6] = ss;
  __syncthreads();
  float tot = sm[0]+sm[1]+sm[2]+sm[3];
  float scale = rsqrtf(tot*(1.f/DI) + 1e-5f);
  f32x4 wv = *(const f32x4*)(rms_w + t*4);
  gv.x *= scale*wv.x; gv.y *= scale*wv.y; gv.z *= scale*wv.z; gv.w *= scale*wv.w;
  *(f32x4*)gp = gv;
}

extern "C" void kernel_launch(void* const* d_in, const int* in_sizes, int n_in,
                              void* d_out, int out_size, void* d_ws, size_t ws_size,
                              hipStream_t stream) {
  const float* x      = (const float*)d_in[0];
  const float* ln_w   = (const float*)d_in[1];
  const float* ln_b   = (const float*)d_in[2];
  const float* in_w   = (const float*)d_in[3];
  const float* conv_w = (const float*)d_in[4];
  const float* conv_b = (const float*)d_in[5];
  const float* dt_b   = (const float*)d_in[6];
  const float* A_log  = (const float*)d_in[7];
  const float* Dp     = (const float*)d_in[8];
  const float* rms_w  = (const float*)d_in[9];
  const float* out_w  = (const float*)d_in[10];
  float* out = (float*)d_out;
  char* ws = (char*)d_ws;

  size_t o = 0;
  float* stats = (float*)(ws+o);           o += (size_t)NROWS*2*4;        // 0.13 MB
  unsigned short* w1h = (unsigned short*)(ws+o); o += (size_t)DIPP*DM*2;  // 2.36 MB
  unsigned short* w1l = (unsigned short*)(ws+o); o += (size_t)DIPP*DM*2;  // 2.36 MB
  unsigned short* w2h = (unsigned short*)(ws+o); o += (size_t)DM*DI*2;    // 1.05 MB
  unsigned short* w2l = (unsigned short*)(ws+o); o += (size_t)DM*DI*2;    // 1.05 MB
  float* z    = (float*)(ws+o);            o += (size_t)NROWS*DI*4;       // 67.1 MB
  float* xbc  = (float*)(ws+o);            o += (size_t)NROWS*CONVD*4;    // 75.5 MB
  float* dtp  = (float*)(ws+o);            o += (size_t)NROWS*NH*4;       // 1.05 MB
  float* acum = (float*)(ws+o);            o += (size_t)BATCH*NH*SEQL*4;  // 1.05 MB
  float* cdec = (float*)(ws+o);            o += (size_t)BATCH*NH*64*4;    // 16 KB
  float* bcc  = (float*)(ws+o);            o += (size_t)NROWS*128*4;      // 8.39 MB
  float* Sreg = (float*)(ws+o);            o += (size_t)BATCH*64*NH*4096*4; // 67.1 MB
  if(o > ws_size) return;   // diagnostic: clean validation failure instead of OOB fault

  k_stats<<<NROWS, 256, 0, stream>>>(x, stats);
  k_wsplit<<<dim3(DIPP/32, DM/32), dim3(32,8), 0, stream>>>(in_w,  w1h, w1l, DM, DIP);
  k_wsplit<<<dim3(DM/32,  DI/32), dim3(32,8), 0, stream>>>(out_w, w2h, w2l, DI, DM);
  k_gemm_in<<<(NROWS/128)*(DIPP/128), 256, 0, stream>>>(x, stats, ln_w, ln_b, w1h, w1l, z, xbc);
  k_dt<<<NROWS, 256, 0, stream>>>(x, stats, ln_w, ln_b, in_w, dt_b, dtp);
  k_convBC<<<(NROWS*32)/256, 256, 0, stream>>>(xbc, conv_w, conv_b, bcc);
  k_acum<<<dim3(BATCH*NH, 64), 64, 0, stream>>>(dtp, A_log, acum, cdec);
  k_states<<<dim3(BATCH*64, NH), 256, 0, stream>>>(xbc, bcc, dtp, acum, conv_w, conv_b, Sreg);
  k_scan<<<(BATCH*NH*4096)/256, 256, 0, stream>>>(Sreg, cdec);
  k_y<<<dim3(BATCH*64, NH), 256, 0, stream>>>(xbc, bcc, dtp, acum, conv_w, conv_b, Dp, Sreg);
  k_gate<<<NROWS, 256, 0, stream>>>(Sreg, z, rms_w);
  k_gemm_out<<<(NROWS/128)*(DM/128), 256, 0, stream>>>(Sreg, w2h, w2l, x, out);
}

// Round 5
// 782.299 us; speedup vs baseline: 3.3225x; 3.3225x over previous
//
#include <hip/hip_runtime.h>
#include <hip/hip_bf16.h>
#include <cstddef>

#define BATCH  4
#define SEQL   4096
#define DM     512
#define DIP    2192
#define DIPP   2304
#define DI     1024
#define DST    64
#define NH     16
#define HD     64
#define CONVD  1152
#define NROWS  (BATCH*SEQL)

typedef __attribute__((ext_vector_type(8))) short short8;
typedef __attribute__((ext_vector_type(4))) float f32x4;

__device__ __forceinline__ float silu_f(float v){ return v/(1.f+__expf(-v)); }

__device__ __forceinline__ unsigned short bf16_rne(float x){
  unsigned u = __float_as_uint(x);
  unsigned r = u + 0x7FFFu + ((u>>16)&1u);
  return (unsigned short)(r>>16);
}
__device__ __forceinline__ float bf16_to_f(unsigned short h){
  return __uint_as_float(((unsigned)h)<<16);
}

// ---------------- per-row LN stats ----------------
__global__ __launch_bounds__(256)
void k_stats(const float* __restrict__ x, float* __restrict__ stats){
  __shared__ float sm[8];
  int row = blockIdx.x, t = threadIdx.x;
  const float* xr = x + (size_t)row*DM;
  float v0 = xr[t], v1 = xr[t+256];
  float s = v0+v1, s2 = v0*v0+v1*v1;
  for(int o=32;o;o>>=1){ s += __shfl_down(s,o); s2 += __shfl_down(s2,o); }
  if((t&63)==0){ sm[t>>6]=s; sm[4+(t>>6)]=s2; }
  __syncthreads();
  if(t==0){
    float su = sm[0]+sm[1]+sm[2]+sm[3];
    float sq = sm[4]+sm[5]+sm[6]+sm[7];
    float mu = su*(1.f/DM);
    float rs = rsqrtf(sq*(1.f/DM) - mu*mu + 1e-5f);
    stats[row*2] = mu; stats[row*2+1] = rs;
  }
}

// ------- transpose + split fp32[K][N] -> bf16 hi/lo [Npad][K]; pad rows zeroed -------
__global__ void k_wsplit(const float* __restrict__ src, unsigned short* __restrict__ dh,
                         unsigned short* __restrict__ dl, int K, int N){
  __shared__ float sm[32][33];
  int tx = threadIdx.x, ty = threadIdx.y;     // (32,8)
  int n0 = blockIdx.x*32, k0 = blockIdx.y*32;
  #pragma unroll
  for(int j=0;j<4;j++){
    int k = k0+ty+j*8, n = n0+tx;
    sm[ty+j*8][tx] = (k<K && n<N) ? src[(size_t)k*N+n] : 0.f;
  }
  __syncthreads();
  #pragma unroll
  for(int j=0;j<4;j++){
    int n = n0+ty+j*8, k = k0+tx;
    float v = sm[tx][ty+j*8];
    unsigned short hh = bf16_rne(v);
    dh[(size_t)n*K+k] = hh;
    dl[(size_t)n*K+k] = bf16_rne(v - bf16_to_f(hh));
  }
}

// ---- in_proj GEMM: LN(x) @ in_w, split-bf16 3-MFMA, epilogue scatters z/xbc ----
__global__ __launch_bounds__(256)
void k_gemm_in(const float* __restrict__ x, const float* __restrict__ stats,
               const float* __restrict__ lnw, const float* __restrict__ lnb,
               const unsigned short* __restrict__ Bhg, const unsigned short* __restrict__ Blg,
               float* __restrict__ z, float* __restrict__ xbc){
  __shared__ unsigned short Ah[128][72], Al[128][72], Bh[128][72], Bl[128][72];
  const int ntn = DIPP/128;                    // 18
  int bid = blockIdx.x;
  int tm = bid / ntn, tn = bid % ntn;
  int t = threadIdx.x, lane = t&63, wave = t>>6;
  int wr = (wave>>1)*64, wc = (wave&1)*64, fr = lane&15;
  f32x4 zero = {0.f,0.f,0.f,0.f};
  f32x4 acc[4][4];
  #pragma unroll
  for(int m=0;m<4;m++)
    #pragma unroll
    for(int n=0;n<4;n++) acc[m][n]=zero;
  const int arow = tm*128, bcol = tn*128;
  for(int k0=0; k0<DM; k0+=64){
    __syncthreads();
    #pragma unroll
    for(int i=0;i<8;i++){
      int idx = t + i*256;
      int r = idx>>4, cq = (idx&15)*4;
      int grow = arow + r;
      f32x4 xv = *(const f32x4*)(x + (size_t)grow*DM + k0 + cq);
      float mu = stats[grow*2], rsd = stats[grow*2+1];
      f32x4 wv = *(const f32x4*)(lnw + k0 + cq);
      f32x4 bv = *(const f32x4*)(lnb + k0 + cq);
      #pragma unroll
      for(int j=0;j<4;j++){
        float v = (xv[j]-mu)*rsd*wv[j] + bv[j];
        unsigned short hh = bf16_rne(v);
        Ah[r][cq+j] = hh;
        Al[r][cq+j] = bf16_rne(v - bf16_to_f(hh));
      }
    }
    #pragma unroll
    for(int i=0;i<4;i++){
      int idx = t + i*256;
      int r = idx>>3, c8 = (idx&7)*8;
      *(short8*)(&Bh[r][c8]) = *(const short8*)(Bhg + (size_t)(bcol+r)*DM + k0 + c8);
      *(short8*)(&Bl[r][c8]) = *(const short8*)(Blg + (size_t)(bcol+r)*DM + k0 + c8);
    }
    __syncthreads();
    #pragma unroll
    for(int kk=0;kk<2;kk++){
      int fk = kk*32 + ((lane>>4)<<3);
      short8 afh[4], afl[4], bfh[4], bfl[4];
      #pragma unroll
      for(int m=0;m<4;m++){
        afh[m] = *(const short8*)(&Ah[wr+m*16+fr][fk]);
        afl[m] = *(const short8*)(&Al[wr+m*16+fr][fk]);
      }
      #pragma unroll
      for(int n=0;n<4;n++){
        bfh[n] = *(const short8*)(&Bh[wc+n*16+fr][fk]);
        bfl[n] = *(const short8*)(&Bl[wc+n*16+fr][fk]);
      }
      #pragma unroll
      for(int m=0;m<4;m++)
        #pragma unroll
        for(int n=0;n<4;n++){
          acc[m][n] = __builtin_amdgcn_mfma_f32_16x16x32_bf16(afh[m], bfh[n], acc[m][n], 0,0,0);
          acc[m][n] = __builtin_amdgcn_mfma_f32_16x16x32_bf16(afh[m], bfl[n], acc[m][n], 0,0,0);
          acc[m][n] = __builtin_amdgcn_mfma_f32_16x16x32_bf16(afl[m], bfh[n], acc[m][n], 0,0,0);
        }
    }
  }
  int fq = (lane>>4)*4;
  #pragma unroll
  for(int m=0;m<4;m++)
    #pragma unroll
    for(int n=0;n<4;n++)
      #pragma unroll
      for(int j=0;j<4;j++){
        int row = arow + wr + m*16 + fq + j;
        int col = bcol + wc + n*16 + fr;
        float v = acc[m][n][j];
        if(col < DI) z[(size_t)row*DI + col] = v;
        else if(col < DI+CONVD) xbc[(size_t)row*CONVD + (col-DI)] = v;
        // cols >= 2176: dt handled exactly by k_dt; pad cols dropped
      }
}

// ---- out_proj GEMM: g(Sreg scattered) @ out_w + x -> out ----
__global__ __launch_bounds__(256)
void k_gemm_out(const float* __restrict__ G, const unsigned short* __restrict__ Bhg,
                const unsigned short* __restrict__ Blg, const float* __restrict__ resid,
                float* __restrict__ outp){
  __shared__ unsigned short Ah[128][72], Al[128][72], Bh[128][72], Bl[128][72];
  const int ntn = DM/128;                      // 4
  int bid = blockIdx.x;
  int tm = bid / ntn, tn = bid % ntn;
  int t = threadIdx.x, lane = t&63, wave = t>>6;
  int wr = (wave>>1)*64, wc = (wave&1)*64, fr = lane&15;
  f32x4 zero = {0.f,0.f,0.f,0.f};
  f32x4 acc[4][4];
  #pragma unroll
  for(int m=0;m<4;m++)
    #pragma unroll
    for(int n=0;n<4;n++) acc[m][n]=zero;
  const int arow = tm*128, bcol = tn*128;
  for(int k0=0; k0<DI; k0+=64){
    __syncthreads();
    int h = k0>>6;
    #pragma unroll
    for(int i=0;i<8;i++){
      int idx = t + i*256;
      int r = idx>>4, cq = (idx&15)*4;
      int grow = arow + r;
      int bb = grow>>12, cc = (grow>>6)&63, lin = grow&63;
      size_t base = ((size_t)((bb*64+cc)*NH + h))*4096 + (size_t)lin*64;
      f32x4 gv = *(const f32x4*)(G + base + cq);
      #pragma unroll
      for(int j=0;j<4;j++){
        unsigned short hh = bf16_rne(gv[j]);
        Ah[r][cq+j] = hh;
        Al[r][cq+j] = bf16_rne(gv[j] - bf16_to_f(hh));
      }
    }
    #pragma unroll
    for(int i=0;i<4;i++){
      int idx = t + i*256;
      int r = idx>>3, c8 = (idx&7)*8;
      *(short8*)(&Bh[r][c8]) = *(const short8*)(Bhg + (size_t)(bcol+r)*DI + k0 + c8);
      *(short8*)(&Bl[r][c8]) = *(const short8*)(Blg + (size_t)(bcol+r)*DI + k0 + c8);
    }
    __syncthreads();
    #pragma unroll
    for(int kk=0;kk<2;kk++){
      int fk = kk*32 + ((lane>>4)<<3);
      short8 afh[4], afl[4], bfh[4], bfl[4];
      #pragma unroll
      for(int m=0;m<4;m++){
        afh[m] = *(const short8*)(&Ah[wr+m*16+fr][fk]);
        afl[m] = *(const short8*)(&Al[wr+m*16+fr][fk]);
      }
      #pragma unroll
      for(int n=0;n<4;n++){
        bfh[n] = *(const short8*)(&Bh[wc+n*16+fr][fk]);
        bfl[n] = *(const short8*)(&Bl[wc+n*16+fr][fk]);
      }
      #pragma unroll
      for(int m=0;m<4;m++)
        #pragma unroll
        for(int n=0;n<4;n++){
          acc[m][n] = __builtin_amdgcn_mfma_f32_16x16x32_bf16(afh[m], bfh[n], acc[m][n], 0,0,0);
          acc[m][n] = __builtin_amdgcn_mfma_f32_16x16x32_bf16(afh[m], bfl[n], acc[m][n], 0,0,0);
          acc[m][n] = __builtin_amdgcn_mfma_f32_16x16x32_bf16(afl[m], bfh[n], acc[m][n], 0,0,0);
        }
    }
  }
  int fq = (lane>>4)*4;
  #pragma unroll
  for(int m=0;m<4;m++)
    #pragma unroll
    for(int n=0;n<4;n++)
      #pragma unroll
      for(int j=0;j<4;j++){
        int row = arow + wr + m*16 + fq + j;
        int col = bcol + wc + n*16 + fr;
        outp[(size_t)row*DM + col] = acc[m][n][j] + resid[(size_t)row*DM + col];
      }
}

// ---------------- exact fp32 dt ----------------
__global__ __launch_bounds__(256)
void k_dt(const float* __restrict__ x, const float* __restrict__ stats,
          const float* __restrict__ lnw, const float* __restrict__ lnb,
          const float* __restrict__ in_w, const float* __restrict__ dt_bias,
          float* __restrict__ dtp){
  __shared__ float red[64];
  int row = blockIdx.x, t = threadIdx.x;
  float mu = stats[row*2], rs = stats[row*2+1];
  float a[16];
  #pragma unroll
  for(int j=0;j<16;j++) a[j]=0.f;
  #pragma unroll
  for(int i=0;i<2;i++){
    int k = t + i*256;
    float hv = (x[(size_t)row*DM + k]-mu)*rs*lnw[k] + lnb[k];
    const float* wr2 = in_w + (size_t)k*DIP + (DIP-NH);
    #pragma unroll
    for(int j=0;j<16;j++) a[j] += hv * wr2[j];
  }
  for(int o=32;o;o>>=1){
    #pragma unroll
    for(int j=0;j<16;j++) a[j] += __shfl_down(a[j],o);
  }
  if((t&63)==0){
    #pragma unroll
    for(int j=0;j<16;j++) red[(t>>6)*16+j] = a[j];
  }
  __syncthreads();
  if(t<16){
    float v = red[t] + red[16+t] + red[32+t] + red[48+t] + dt_bias[t];
    dtp[(size_t)row*NH + t] = (v > 20.f) ? v : log1pf(__expf(v));
  }
}

// ---------------- conv+silu for B/C channels only -> bcc[row][128] ----------------
__global__ __launch_bounds__(256)
void k_convBC(const float* __restrict__ xbc, const float* __restrict__ cw,
              const float* __restrict__ cb, float* __restrict__ bcc){
  int gid = blockIdx.x*256 + threadIdx.x;     // NROWS*32
  int c4 = gid & 31, row = gid >> 5;
  int c = c4*4;                                // channel 1024+c .. +3
  int lb = row & (SEQL-1);
  const float* base = xbc + (size_t)row*CONVD + DI + c;
  f32x4 w0 = *(const f32x4*)(cw + (size_t)(DI+c+0)*4);
  f32x4 w1 = *(const f32x4*)(cw + (size_t)(DI+c+1)*4);
  f32x4 w2 = *(const f32x4*)(cw + (size_t)(DI+c+2)*4);
  f32x4 w3 = *(const f32x4*)(cw + (size_t)(DI+c+3)*4);
  f32x4 r = { cb[DI+c], cb[DI+c+1], cb[DI+c+2], cb[DI+c+3] };
  #pragma unroll
  for(int k=0;k<4;k++){
    if(lb-3+k >= 0){
      f32x4 xv = *(const f32x4*)(base + (long)(k-3)*CONVD);
      r.x += xv.x*w0[k]; r.y += xv.y*w1[k]; r.z += xv.z*w2[k]; r.w += xv.w*w3[k];
    }
  }
  r.x = silu_f(r.x); r.y = silu_f(r.y); r.z = silu_f(r.z); r.w = silu_f(r.w);
  *(f32x4*)(bcc + (size_t)row*128 + c) = r;
}

// ---------------- per-chunk cumsum of dt*A ----------------
__global__ void k_acum(const float* __restrict__ dtp, const float* __restrict__ A_log,
                       float* __restrict__ acum, float* __restrict__ cdec){
  int bh = blockIdx.x;                 // b*16+h
  int h = bh & 15;
  int c = blockIdx.y, l = threadIdx.x; // 64 threads
  int row = (bh>>4)*SEQL + c*64 + l;
  float a = -__expf(A_log[h]);
  float v = dtp[(size_t)row*NH + h] * a;
  for(int o=1;o<64;o<<=1){ float u = __shfl_up(v,o); if(l>=o) v += u; }
  acum[(size_t)bh*SEQL + c*64 + l] = v;
  if(l==63) cdec[bh*64 + c] = __expf(v);
}

// ---------------- Phase A: chunk states (conv-recompute for x-head) ----------------
// grid (NH, BATCH*64): consecutive blocks share (b,c) -> L2 reuse of bcc/xbc rows
__global__ __launch_bounds__(256)
void k_states(const float* __restrict__ xbc, const float* __restrict__ bcc,
              const float* __restrict__ dtp, const float* __restrict__ acum,
              const float* __restrict__ cw, const float* __restrict__ cb,
              float* __restrict__ S){
  int h = blockIdx.x, bc = blockIdx.y;
  int b = bc >> 6, c = bc & 63;
  __shared__ float Bd[64][68];
  __shared__ float Xs[64][68];
  __shared__ float raw[67*64];
  __shared__ f32x4 wc4[64];
  __shared__ float cbv[64], acs[64], dts[64];
  int t = threadIdx.x;
  if(t < 64){
    acs[t] = acum[((size_t)(b*NH+h))*SEQL + c*64 + t];
    dts[t] = dtp[(size_t)(b*SEQL + c*64 + t)*NH + h];
    wc4[t] = *(const f32x4*)(cw + (size_t)(h*HD + t)*4);
    cbv[t] = cb[h*HD + t];
  }
  __syncthreads();
  #pragma unroll
  for(int i=0;i<4;i++){
    int idx = t + i*256;
    int l = idx>>4, n4 = (idx&15)*4;
    f32x4 bv = *(const f32x4*)(bcc + (size_t)(b*SEQL + c*64 + l)*128 + n4);
    float dec = __expf(acs[63] - acs[l]);
    *(f32x4*)&Bd[l][n4] = bv * dec;
  }
  #pragma unroll
  for(int i=0;i<5;i++){
    int idx = t + i*256;
    if(idx < 67*16){
      int rr = idx>>4, p4 = (idx&15)*4;
      int wb = c*64 - 3 + rr;
      f32x4 xv = {0.f,0.f,0.f,0.f};
      if(wb >= 0) xv = *(const f32x4*)(xbc + (size_t)(b*SEQL + wb)*CONVD + h*HD + p4);
      *(f32x4*)&raw[rr*64 + p4] = xv;
    }
  }
  __syncthreads();
  {
    int l = t>>2, q = t&3;
    float dtv = dts[l];
    #pragma unroll
    for(int jj=0;jj<16;jj++){
      int p = q*16 + jj;
      f32x4 w = wc4[p];
      float a = cbv[p] + raw[(l+0)*64+p]*w.x + raw[(l+1)*64+p]*w.y
              + raw[(l+2)*64+p]*w.z + raw[(l+3)*64+p]*w.w;
      Xs[l][p] = silu_f(a) * dtv;
    }
  }
  __syncthreads();
  int n = t>>2, p0 = (t&3)*16;
  f32x4 a0={0.f,0.f,0.f,0.f}, a1=a0, a2=a0, a3=a0;
  #pragma unroll 2
  for(int ll=0; ll<64; ll++){
    float bnd = Bd[ll][n];
    const float* xp = &Xs[ll][p0];
    a0 += bnd * *(const f32x4*)(xp);
    a1 += bnd * *(const f32x4*)(xp+4);
    a2 += bnd * *(const f32x4*)(xp+8);
    a3 += bnd * *(const f32x4*)(xp+12);
  }
  float* op = S + ((size_t)(bc*NH + h))*4096 + n*64 + p0;
  *(f32x4*)(op)    = a0;
  *(f32x4*)(op+4)  = a1;
  *(f32x4*)(op+8)  = a2;
  *(f32x4*)(op+12) = a3;
}

// ---------------- Phase B: inter-chunk scan (prev in-place) ----------------
__global__ void k_scan(float* __restrict__ S, const float* __restrict__ cdec){
  int g = blockIdx.x*256 + threadIdx.x;  // BATCH*NH*4096
  int bh = g >> 12;
  int pn = g & 4095;
  int b = bh >> 4, h = bh & 15;
  const float* cd = cdec + bh*64;
  float s = 0.f;
  for(int c=0;c<64;c++){
    size_t idx = ((size_t)((b*64 + c)*NH + h))*4096 + pn;
    float v = S[idx];
    float d = cd[c];
    S[idx] = s;
    s = s*d + v;
  }
}

// ---------------- Phase C: Y written in-place over prev slot ----------------
// r3/r4 lesson: 8 f32x4 accumulators + auto-unroll over two LDS matrices spilled
// ~3KB/thread to scratch (WRITE_SIZE 3.6GB vs 67MB algorithmic). This version keeps
// ONE set of 4 f32x4 accumulators (off-diag term folded in by pre-scaling C with
// exp(ac[l])) and pins unroll factors.
__global__ __launch_bounds__(256)
void k_y(const float* __restrict__ xbc, const float* __restrict__ bcc,
         const float* __restrict__ dtp, const float* __restrict__ acum,
         const float* __restrict__ cw, const float* __restrict__ cb,
         const float* __restrict__ Dp, float* __restrict__ Sreg){
  int h = blockIdx.x, bc = blockIdx.y;
  int b = bc >> 6, c = bc & 63;
  __shared__ float Cs[64][68];
  __shared__ float BM[64][68];         // B, then overwritten with M
  __shared__ float Xr[64][68];
  __shared__ float PsRaw[64*68];       // raw x [67*64], then Ps [s*68+p]
  __shared__ f32x4 wc4[64];
  __shared__ float cbv[64], acs[64], dts[64];
  int t = threadIdx.x;
  float* Sslot = Sreg + ((size_t)(bc*NH + h))*4096;
  // ---- phase 1: stage B, C, raw x, scalars ----
  if(t < 64){
    acs[t] = acum[((size_t)(b*NH+h))*SEQL + c*64 + t];
    dts[t] = dtp[(size_t)(b*SEQL + c*64 + t)*NH + h];
    wc4[t] = *(const f32x4*)(cw + (size_t)(h*HD + t)*4);
    cbv[t] = cb[h*HD + t];
  }
  #pragma unroll
  for(int i=0;i<4;i++){
    int idx = t + i*256;
    int l = idx>>4, n4 = (idx&15)*4;
    const float* bp = bcc + (size_t)(b*SEQL + c*64 + l)*128;
    *(f32x4*)&BM[l][n4] = *(const f32x4*)(bp + n4);       // B
    *(f32x4*)&Cs[l][n4] = *(const f32x4*)(bp + 64 + n4);  // C
  }
  #pragma unroll
  for(int i=0;i<5;i++){
    int idx = t + i*256;
    if(idx < 67*16){
      int rr = idx>>4, p4 = (idx&15)*4;
      int wb = c*64 - 3 + rr;
      f32x4 xv = {0.f,0.f,0.f,0.f};
      if(wb >= 0) xv = *(const f32x4*)(xbc + (size_t)(b*SEQL + wb)*CONVD + h*HD + p4);
      *(f32x4*)&PsRaw[rr*64 + p4] = xv;
    }
  }
  __syncthreads();
  // ---- phase 2: conv + silu -> Xr ----
  {
    int l = t>>2, q = t&3;
    #pragma unroll
    for(int jj=0;jj<16;jj++){
      int p = q*16 + jj;
      f32x4 w = wc4[p];
      float a = cbv[p] + PsRaw[(l+0)*64+p]*w.x + PsRaw[(l+1)*64+p]*w.y
              + PsRaw[(l+2)*64+p]*w.z + PsRaw[(l+3)*64+p]*w.w;
      Xr[l][p] = silu_f(a);
    }
  }
  __syncthreads();
  // ---- phase 3: G[l][s] = sum_n C[l][n]*B[s][n] (registers g[16] only) ----
  int gl = t & 63, s0 = (t>>6)*16;
  float g[16];
  #pragma unroll
  for(int j=0;j<16;j++) g[j]=0.f;
  #pragma unroll 1
  for(int n4=0;n4<64;n4+=4){
    f32x4 cv = *(const f32x4*)&Cs[gl][n4];
    #pragma unroll
    for(int j=0;j<16;j++){
      f32x4 bv = *(const f32x4*)&BM[s0+j][n4];
      g[j] += cv.x*bv.x + cv.y*bv.y + cv.z*bv.z + cv.w*bv.w;
    }
  }
  __syncthreads();   // all G reads of BM done before M overwrite
  // ---- phase 4: M over BM, and stage Ps over raw (conv done, G done) ----
  {
    float aclg = acs[gl];
    #pragma unroll
    for(int j=0;j<16;j++){
      int s = s0 + j;
      BM[gl][s] = (s <= gl) ? g[j]*__expf(aclg - acs[s])*dts[s] : 0.f;
    }
  }
  #pragma unroll
  for(int i=0;i<4;i++){
    int idx = t + i*256;
    int s = idx>>4, p4 = (idx&15)*4;
    f32x4 pv = *(const f32x4*)(Sslot + s*64 + p4);
    *(f32x4*)&PsRaw[s*68 + p4] = pv;
  }
  __syncthreads();
  // ---- phase 5: Y[l][p] = D*X[l] + sum_s M[l][s]*Xr[s] + sum_s (eal*C[l][s])*Ps[s]
  {
    int l = t>>2, p0 = (t&3)*16;
    float eal = __expf(acs[l]);
    float Dh = Dp[h];
    const float* xl = &Xr[l][p0];
    f32x4 a0 = Dh * *(const f32x4*)(xl);
    f32x4 a1 = Dh * *(const f32x4*)(xl+4);
    f32x4 a2 = Dh * *(const f32x4*)(xl+8);
    f32x4 a3 = Dh * *(const f32x4*)(xl+12);
    #pragma unroll 2
    for(int s=0;s<64;s++){
      float m = BM[l][s];
      const float* xp = &Xr[s][p0];
      a0 += m * *(const f32x4*)(xp);
      a1 += m * *(const f32x4*)(xp+4);
      a2 += m * *(const f32x4*)(xp+8);
      a3 += m * *(const f32x4*)(xp+12);
    }
    #pragma unroll 2
    for(int s=0;s<64;s++){
      float cv = eal * Cs[l][s];
      const float* pp = &PsRaw[s*68 + p0];
      a0 += cv * *(const f32x4*)(pp);
      a1 += cv * *(const f32x4*)(pp+4);
      a2 += cv * *(const f32x4*)(pp+8);
      a3 += cv * *(const f32x4*)(pp+12);
    }
    float* yp = Sslot + l*64 + p0;   // in-place over prev (staged to LDS already)
    *(f32x4*)(yp)    = a0;
    *(f32x4*)(yp+4)  = a1;
    *(f32x4*)(yp+8)  = a2;
    *(f32x4*)(yp+12) = a3;
  }
}

// ---------------- gate + RMSNorm, in-place over y (scattered layout) ----------------
__global__ __launch_bounds__(256)
void k_gate(float* __restrict__ Sreg, const float* __restrict__ z,
            const float* __restrict__ rms_w){
  __shared__ float sm[4];
  int row = blockIdx.x, t = threadIdx.x;
  int b = row>>12, cc = (row>>6)&63, lin = row&63;
  int h = t>>4, p = (t&15)*4;
  float* gp = Sreg + ((size_t)((b*64+cc)*NH + h))*4096 + (size_t)lin*64 + p;
  f32x4 yv = *(const f32x4*)gp;
  f32x4 zv = *(const f32x4*)(z + (size_t)row*DI + t*4);
  f32x4 gv;
  gv.x = yv.x * silu_f(zv.x);
  gv.y = yv.y * silu_f(zv.y);
  gv.z = yv.z * silu_f(zv.z);
  gv.w = yv.w * silu_f(zv.w);
  float ss = gv.x*gv.x + gv.y*gv.y + gv.z*gv.z + gv.w*gv.w;
  for(int o=32;o;o>>=1) ss += __shfl_down(ss,o);
  if((t&63)==0) sm[t>>6] = ss;
  __syncthreads();
  float tot = sm[0]+sm[1]+sm[2]+sm[3];
  float scale = rsqrtf(tot*(1.f/DI) + 1e-5f);
  f32x4 wv = *(const f32x4*)(rms_w + t*4);
  gv.x *= scale*wv.x; gv.y *= scale*wv.y; gv.z *= scale*wv.z; gv.w *= scale*wv.w;
  *(f32x4*)gp = gv;
}

extern "C" void kernel_launch(void* const* d_in, const int* in_sizes, int n_in,
                              void* d_out, int out_size, void* d_ws, size_t ws_size,
                              hipStream_t stream) {
  const float* x      = (const float*)d_in[0];
  const float* ln_w   = (const float*)d_in[1];
  const float* ln_b   = (const float*)d_in[2];
  const float* in_w   = (const float*)d_in[3];
  const float* conv_w = (const float*)d_in[4];
  const float* conv_b = (const float*)d_in[5];
  const float* dt_b   = (const float*)d_in[6];
  const float* A_log  = (const float*)d_in[7];
  const float* Dp     = (const float*)d_in[8];
  const float* rms_w  = (const float*)d_in[9];
  const float* out_w  = (const float*)d_in[10];
  float* out = (float*)d_out;
  char* ws = (char*)d_ws;

  size_t o = 0;
  float* stats = (float*)(ws+o);           o += (size_t)NROWS*2*4;        // 0.13 MB
  unsigned short* w1h = (unsigned short*)(ws+o); o += (size_t)DIPP*DM*2;  // 2.36 MB
  unsigned short* w1l = (unsigned short*)(ws+o); o += (size_t)DIPP*DM*2;  // 2.36 MB
  unsigned short* w2h = (unsigned short*)(ws+o); o += (size_t)DM*DI*2;    // 1.05 MB
  unsigned short* w2l = (unsigned short*)(ws+o); o += (size_t)DM*DI*2;    // 1.05 MB
  float* z    = (float*)(ws+o);            o += (size_t)NROWS*DI*4;       // 67.1 MB
  float* xbc  = (float*)(ws+o);            o += (size_t)NROWS*CONVD*4;    // 75.5 MB
  float* dtp  = (float*)(ws+o);            o += (size_t)NROWS*NH*4;       // 1.05 MB
  float* acum = (float*)(ws+o);            o += (size_t)BATCH*NH*SEQL*4;  // 1.05 MB
  float* cdec = (float*)(ws+o);            o += (size_t)BATCH*NH*64*4;    // 16 KB
  float* bcc  = (float*)(ws+o);            o += (size_t)NROWS*128*4;      // 8.39 MB
  float* Sreg = (float*)(ws+o);            o += (size_t)BATCH*64*NH*4096*4; // 67.1 MB
  if(o > ws_size) return;   // diagnostic: clean validation failure instead of OOB fault

  k_stats<<<NROWS, 256, 0, stream>>>(x, stats);
  k_wsplit<<<dim3(DIPP/32, DM/32), dim3(32,8), 0, stream>>>(in_w,  w1h, w1l, DM, DIP);
  k_wsplit<<<dim3(DM/32,  DI/32), dim3(32,8), 0, stream>>>(out_w, w2h, w2l, DI, DM);
  k_gemm_in<<<(NROWS/128)*(DIPP/128), 256, 0, stream>>>(x, stats, ln_w, ln_b, w1h, w1l, z, xbc);
  k_dt<<<NROWS, 256, 0, stream>>>(x, stats, ln_w, ln_b, in_w, dt_b, dtp);
  k_convBC<<<(NROWS*32)/256, 256, 0, stream>>>(xbc, conv_w, conv_b, bcc);
  k_acum<<<dim3(BATCH*NH, 64), 64, 0, stream>>>(dtp, A_log, acum, cdec);
  k_states<<<dim3(NH, BATCH*64), 256, 0, stream>>>(xbc, bcc, dtp, acum, conv_w, conv_b, Sreg);
  k_scan<<<(BATCH*NH*4096)/256, 256, 0, stream>>>(Sreg, cdec);
  k_y<<<dim3(NH, BATCH*64), 256, 0, stream>>>(xbc, bcc, dtp, acum, conv_w, conv_b, Dp, Sreg);
  k_gate<<<NROWS, 256, 0, stream>>>(Sreg, z, rms_w);
  k_gemm_out<<<(NROWS/128)*(DM/128), 256, 0, stream>>>(Sreg, w2h, w2l, x, out);
}

// Round 7
// 677.922 us; speedup vs baseline: 3.8340x; 1.1540x over previous
//
#include <hip/hip_runtime.h>
#include <hip/hip_bf16.h>
#include <cstddef>

#define BATCH  4
#define SEQL   4096
#define DM     512
#define DIP    2192
#define NIP    2176            // in_proj cols actually needed (z + xbc)
#define DI     1024
#define DST    64
#define NH     16
#define HD     64
#define CONVD  1152
#define NROWS  (BATCH*SEQL)

typedef __attribute__((ext_vector_type(8))) short short8;
typedef __attribute__((ext_vector_type(4))) float f32x4;
typedef __attribute__((ext_vector_type(4))) unsigned short u16x4;

__device__ __forceinline__ float silu_f(float v){ return v/(1.f+__expf(-v)); }

__device__ __forceinline__ unsigned short bf16_rne(float x){
  unsigned u = __float_as_uint(x);
  unsigned r = u + 0x7FFFu + ((u>>16)&1u);
  return (unsigned short)(r>>16);
}
__device__ __forceinline__ float bf16_to_f(unsigned short h){
  return __uint_as_float(((unsigned)h)<<16);
}

// ---------------- LN stats + split-bf16 LN output planes Ai[row][2][DM] ----------------
__global__ __launch_bounds__(256)
void k_stats(const float* __restrict__ x, const float* __restrict__ lnw,
             const float* __restrict__ lnb, float* __restrict__ stats,
             unsigned short* __restrict__ Ai){
  __shared__ float sm[8];
  int row = blockIdx.x, t = threadIdx.x;
  const float* xr = x + (size_t)row*DM;
  float v0 = xr[t], v1 = xr[t+256];
  float s = v0+v1, s2 = v0*v0+v1*v1;
  for(int o=32;o;o>>=1){ s += __shfl_down(s,o); s2 += __shfl_down(s2,o); }
  if((t&63)==0){ sm[t>>6]=s; sm[4+(t>>6)]=s2; }
  __syncthreads();
  float su = sm[0]+sm[1]+sm[2]+sm[3];
  float sq = sm[4]+sm[5]+sm[6]+sm[7];
  float mu = su*(1.f/DM);
  float rs = rsqrtf(sq*(1.f/DM) - mu*mu + 1e-5f);
  if(t==0){ stats[row*2]=mu; stats[row*2+1]=rs; }
  unsigned short* ap = Ai + (size_t)row*2*DM;
  float a0 = (v0-mu)*rs*lnw[t] + lnb[t];
  unsigned short h0 = bf16_rne(a0);
  ap[t] = h0; ap[DM+t] = bf16_rne(a0 - bf16_to_f(h0));
  float a1 = (v1-mu)*rs*lnw[t+256] + lnb[t+256];
  unsigned short h1 = bf16_rne(a1);
  ap[t+256] = h1; ap[DM+t+256] = bf16_rne(a1 - bf16_to_f(h1));
}

// ------- transpose + split fp32 src[K][srcStride] (cols 0..N-1) -> bf16 hi/lo [N][K] -------
__global__ void k_wsplit(const float* __restrict__ src, unsigned short* __restrict__ dh,
                         unsigned short* __restrict__ dl, int K, int N, int srcStride){
  __shared__ float sm[32][33];
  int tx = threadIdx.x, ty = threadIdx.y;     // (32,8)
  int n0 = blockIdx.x*32, k0 = blockIdx.y*32;
  #pragma unroll
  for(int j=0;j<4;j++){
    int k = k0+ty+j*8, n = n0+tx;
    sm[ty+j*8][tx] = (k<K && n<N) ? src[(size_t)k*srcStride+n] : 0.f;
  }
  __syncthreads();
  #pragma unroll
  for(int j=0;j<4;j++){
    int n = n0+ty+j*8, k = k0+tx;
    if(n < N){
      float v = sm[tx][ty+j*8];
      unsigned short hh = bf16_rne(v);
      dh[(size_t)n*K+k] = hh;
      dl[(size_t)n*K+k] = bf16_rne(v - bf16_to_f(hh));
    }
  }
}

// ---- in_proj GEMM: Ai(hi/lo bf16) @ w1, 3-MFMA split, epilogue scatters z/xbc ----
__global__ __launch_bounds__(256)
void k_gemm_in(const unsigned short* __restrict__ Ai,
               const unsigned short* __restrict__ Bhg, const unsigned short* __restrict__ Blg,
               float* __restrict__ z, float* __restrict__ xbc){
  __shared__ unsigned short Ah[128][76], Al[128][76], Bh[128][76], Bl[128][76];
  const int ntn = NIP/128;                     // 17
  int nwg = gridDim.x;
  int bid0 = blockIdx.x;
  int bid = (bid0 & 7)*(nwg>>3) + (bid0>>3);   // XCD swizzle (nwg%8==0)
  int tm = bid / ntn, tn = bid % ntn;
  int t = threadIdx.x, lane = t&63, wave = t>>6;
  int wr = (wave>>1)*64, wc = (wave&1)*64, fr = lane&15;
  f32x4 zero = {0.f,0.f,0.f,0.f};
  f32x4 acc[4][4];
  #pragma unroll
  for(int m=0;m<4;m++)
    #pragma unroll
    for(int n=0;n<4;n++) acc[m][n]=zero;
  const int arow = tm*128, bcol = tn*128;
  int plane = (t>>3)&1;                        // uniform per thread across i
  unsigned short* Adst = plane ? &Al[0][0] : &Ah[0][0];
  for(int k0=0; k0<DM; k0+=64){
    __syncthreads();
    #pragma unroll
    for(int i=0;i<8;i++){
      int r = (t>>4) + i*16, c8 = (t&7)*8;
      *(short8*)(Adst + r*76 + c8) =
        *(const short8*)(Ai + ((size_t)(arow+r)*2 + plane)*DM + k0 + c8);
    }
    #pragma unroll
    for(int i=0;i<4;i++){
      int idx = t + i*256;
      int r = idx>>3, c8 = (idx&7)*8;
      *(short8*)(&Bh[r][c8]) = *(const short8*)(Bhg + (size_t)(bcol+r)*DM + k0 + c8);
      *(short8*)(&Bl[r][c8]) = *(const short8*)(Blg + (size_t)(bcol+r)*DM + k0 + c8);
    }
    __syncthreads();
    #pragma unroll
    for(int kk=0;kk<2;kk++){
      int fk = kk*32 + ((lane>>4)<<3);
      short8 afh[4], afl[4], bfh[4], bfl[4];
      #pragma unroll
      for(int m=0;m<4;m++){
        afh[m] = *(const short8*)(&Ah[wr+m*16+fr][fk]);
        afl[m] = *(const short8*)(&Al[wr+m*16+fr][fk]);
      }
      #pragma unroll
      for(int n=0;n<4;n++){
        bfh[n] = *(const short8*)(&Bh[wc+n*16+fr][fk]);
        bfl[n] = *(const short8*)(&Bl[wc+n*16+fr][fk]);
      }
      #pragma unroll
      for(int m=0;m<4;m++)
        #pragma unroll
        for(int n=0;n<4;n++){
          acc[m][n] = __builtin_amdgcn_mfma_f32_16x16x32_bf16(afh[m], bfh[n], acc[m][n], 0,0,0);
          acc[m][n] = __builtin_amdgcn_mfma_f32_16x16x32_bf16(afh[m], bfl[n], acc[m][n], 0,0,0);
          acc[m][n] = __builtin_amdgcn_mfma_f32_16x16x32_bf16(afl[m], bfh[n], acc[m][n], 0,0,0);
        }
    }
  }
  int fq = (lane>>4)*4;
  #pragma unroll
  for(int m=0;m<4;m++)
    #pragma unroll
    for(int n=0;n<4;n++)
      #pragma unroll
      for(int j=0;j<4;j++){
        int row = arow + wr + m*16 + fq + j;
        int col = bcol + wc + n*16 + fr;
        float v = acc[m][n][j];
        if(col < DI) z[(size_t)row*DI + col] = v;
        else xbc[(size_t)row*CONVD + (col-DI)] = v;
      }
}

// ---- out_proj GEMM: g(hi/lo bf16 row-major) @ out_w + x -> out ----
__global__ __launch_bounds__(256)
void k_gemm_out(const unsigned short* __restrict__ gh, const unsigned short* __restrict__ gl,
                const unsigned short* __restrict__ Bhg, const unsigned short* __restrict__ Blg,
                const float* __restrict__ resid, float* __restrict__ outp){
  __shared__ unsigned short Ah[128][76], Al[128][76], Bh[128][76], Bl[128][76];
  const int ntn = DM/128;                      // 4
  int nwg = gridDim.x;
  int bid0 = blockIdx.x;
  int bid = (bid0 & 7)*(nwg>>3) + (bid0>>3);
  int tm = bid / ntn, tn = bid % ntn;
  int t = threadIdx.x, lane = t&63, wave = t>>6;
  int wr = (wave>>1)*64, wc = (wave&1)*64, fr = lane&15;
  f32x4 zero = {0.f,0.f,0.f,0.f};
  f32x4 acc[4][4];
  #pragma unroll
  for(int m=0;m<4;m++)
    #pragma unroll
    for(int n=0;n<4;n++) acc[m][n]=zero;
  const int arow = tm*128, bcol = tn*128;
  int plane = (t>>3)&1;
  unsigned short* Adst = plane ? &Al[0][0] : &Ah[0][0];
  const unsigned short* gsrc = plane ? gl : gh;
  for(int k0=0; k0<DI; k0+=64){
    __syncthreads();
    #pragma unroll
    for(int i=0;i<8;i++){
      int r = (t>>4) + i*16, c8 = (t&7)*8;
      *(short8*)(Adst + r*76 + c8) =
        *(const short8*)(gsrc + (size_t)(arow+r)*DI + k0 + c8);
    }
    #pragma unroll
    for(int i=0;i<4;i++){
      int idx = t + i*256;
      int r = idx>>3, c8 = (idx&7)*8;
      *(short8*)(&Bh[r][c8]) = *(const short8*)(Bhg + (size_t)(bcol+r)*DI + k0 + c8);
      *(short8*)(&Bl[r][c8]) = *(const short8*)(Blg + (size_t)(bcol+r)*DI + k0 + c8);
    }
    __syncthreads();
    #pragma unroll
    for(int kk=0;kk<2;kk++){
      int fk = kk*32 + ((lane>>4)<<3);
      short8 afh[4], afl[4], bfh[4], bfl[4];
      #pragma unroll
      for(int m=0;m<4;m++){
        afh[m] = *(const short8*)(&Ah[wr+m*16+fr][fk]);
        afl[m] = *(const short8*)(&Al[wr+m*16+fr][fk]);
      }
      #pragma unroll
      for(int n=0;n<4;n++){
        bfh[n] = *(const short8*)(&Bh[wc+n*16+fr][fk]);
        bfl[n] = *(const short8*)(&Bl[wc+n*16+fr][fk]);
      }
      #pragma unroll
      for(int m=0;m<4;m++)
        #pragma unroll
        for(int n=0;n<4;n++){
          acc[m][n] = __builtin_amdgcn_mfma_f32_16x16x32_bf16(afh[m], bfh[n], acc[m][n], 0,0,0);
          acc[m][n] = __builtin_amdgcn_mfma_f32_16x16x32_bf16(afh[m], bfl[n], acc[m][n], 0,0,0);
          acc[m][n] = __builtin_amdgcn_mfma_f32_16x16x32_bf16(afl[m], bfh[n], acc[m][n], 0,0,0);
        }
    }
  }
  int fq = (lane>>4)*4;
  #pragma unroll
  for(int m=0;m<4;m++)
    #pragma unroll
    for(int n=0;n<4;n++)
      #pragma unroll
      for(int j=0;j<4;j++){
        int row = arow + wr + m*16 + fq + j;
        int col = bcol + wc + n*16 + fr;
        outp[(size_t)row*DM + col] = acc[m][n][j] + resid[(size_t)row*DM + col];
      }
}

// ---------------- exact fp32 dt ----------------
__global__ __launch_bounds__(256)
void k_dt(const float* __restrict__ x, const float* __restrict__ stats,
          const float* __restrict__ lnw, const float* __restrict__ lnb,
          const float* __restrict__ in_w, const float* __restrict__ dt_bias,
          float* __restrict__ dtp){
  __shared__ float red[64];
  int row = blockIdx.x, t = threadIdx.x;
  float mu = stats[row*2], rs = stats[row*2+1];
  float a[16];
  #pragma unroll
  for(int j=0;j<16;j++) a[j]=0.f;
  #pragma unroll
  for(int i=0;i<2;i++){
    int k = t + i*256;
    float hv = (x[(size_t)row*DM + k]-mu)*rs*lnw[k] + lnb[k];
    const float* wr2 = in_w + (size_t)k*DIP + (DIP-NH);
    #pragma unroll
    for(int j=0;j<16;j++) a[j] += hv * wr2[j];
  }
  for(int o=32;o;o>>=1){
    #pragma unroll
    for(int j=0;j<16;j++) a[j] += __shfl_down(a[j],o);
  }
  if((t&63)==0){
    #pragma unroll
    for(int j=0;j<16;j++) red[(t>>6)*16+j] = a[j];
  }
  __syncthreads();
  if(t<16){
    float v = red[t] + red[16+t] + red[32+t] + red[48+t] + dt_bias[t];
    dtp[(size_t)row*NH + t] = (v > 20.f) ? v : log1pf(__expf(v));
  }
}

// ---------------- conv+silu for B/C channels only -> bcc[row][128] ----------------
__global__ __launch_bounds__(256)
void k_convBC(const float* __restrict__ xbc, const float* __restrict__ cw,
              const float* __restrict__ cb, float* __restrict__ bcc){
  int gid = blockIdx.x*256 + threadIdx.x;     // NROWS*32
  int c4 = gid & 31, row = gid >> 5;
  int c = c4*4;                                // channel 1024+c .. +3
  int lb = row & (SEQL-1);
  const float* base = xbc + (size_t)row*CONVD + DI + c;
  f32x4 w0 = *(const f32x4*)(cw + (size_t)(DI+c+0)*4);
  f32x4 w1 = *(const f32x4*)(cw + (size_t)(DI+c+1)*4);
  f32x4 w2 = *(const f32x4*)(cw + (size_t)(DI+c+2)*4);
  f32x4 w3 = *(const f32x4*)(cw + (size_t)(DI+c+3)*4);
  f32x4 r = { cb[DI+c], cb[DI+c+1], cb[DI+c+2], cb[DI+c+3] };
  #pragma unroll
  for(int k=0;k<4;k++){
    if(lb-3+k >= 0){
      f32x4 xv = *(const f32x4*)(base + (long)(k-3)*CONVD);
      r.x += xv.x*w0[k]; r.y += xv.y*w1[k]; r.z += xv.z*w2[k]; r.w += xv.w*w3[k];
    }
  }
  r.x = silu_f(r.x); r.y = silu_f(r.y); r.z = silu_f(r.z); r.w = silu_f(r.w);
  *(f32x4*)(bcc + (size_t)row*128 + c) = r;
}

// ---------------- per-chunk cumsum of dt*A ----------------
__global__ void k_acum(const float* __restrict__ dtp, const float* __restrict__ A_log,
                       float* __restrict__ acum, float* __restrict__ cdec){
  int bh = blockIdx.x;                 // b*16+h
  int h = bh & 15;
  int c = blockIdx.y, l = threadIdx.x; // 64 threads
  int row = (bh>>4)*SEQL + c*64 + l;
  float a = -__expf(A_log[h]);
  float v = dtp[(size_t)row*NH + h] * a;
  for(int o=1;o<64;o<<=1){ float u = __shfl_up(v,o); if(l>=o) v += u; }
  acum[(size_t)bh*SEQL + c*64 + l] = v;
  if(l==63) cdec[bh*64 + c] = __expf(v);
}

// ---------------- Phase A: chunk states (conv-recompute for x-head) ----------------
__global__ __launch_bounds__(256)
void k_states(const float* __restrict__ xbc, const float* __restrict__ bcc,
              const float* __restrict__ dtp, const float* __restrict__ acum,
              const float* __restrict__ cw, const float* __restrict__ cb,
              float* __restrict__ S){
  int h = blockIdx.x, bc = blockIdx.y;
  int b = bc >> 6, c = bc & 63;
  __shared__ float Bd[64][68];
  __shared__ float Xs[64][68];
  __shared__ float raw[67*64];
  __shared__ f32x4 wc4[64];
  __shared__ float cbv[64], acs[64], dts[64];
  int t = threadIdx.x;
  if(t < 64){
    acs[t] = acum[((size_t)(b*NH+h))*SEQL + c*64 + t];
    dts[t] = dtp[(size_t)(b*SEQL + c*64 + t)*NH + h];
    wc4[t] = *(const f32x4*)(cw + (size_t)(h*HD + t)*4);
    cbv[t] = cb[h*HD + t];
  }
  __syncthreads();
  #pragma unroll
  for(int i=0;i<4;i++){
    int idx = t + i*256;
    int l = idx>>4, n4 = (idx&15)*4;
    f32x4 bv = *(const f32x4*)(bcc + (size_t)(b*SEQL + c*64 + l)*128 + n4);
    float dec = __expf(acs[63] - acs[l]);
    *(f32x4*)&Bd[l][n4] = bv * dec;
  }
  #pragma unroll
  for(int i=0;i<5;i++){
    int idx = t + i*256;
    if(idx < 67*16){
      int rr = idx>>4, p4 = (idx&15)*4;
      int wb = c*64 - 3 + rr;
      f32x4 xv = {0.f,0.f,0.f,0.f};
      if(wb >= 0) xv = *(const f32x4*)(xbc + (size_t)(b*SEQL + wb)*CONVD + h*HD + p4);
      *(f32x4*)&raw[rr*64 + p4] = xv;
    }
  }
  __syncthreads();
  {
    int l = t>>2, q = t&3;
    float dtv = dts[l];
    #pragma unroll
    for(int jj=0;jj<16;jj++){
      int p = q*16 + jj;
      f32x4 w = wc4[p];
      float a = cbv[p] + raw[(l+0)*64+p]*w.x + raw[(l+1)*64+p]*w.y
              + raw[(l+2)*64+p]*w.z + raw[(l+3)*64+p]*w.w;
      Xs[l][p] = silu_f(a) * dtv;
    }
  }
  __syncthreads();
  int n = t>>2, p0 = (t&3)*16;
  f32x4 a0={0.f,0.f,0.f,0.f}, a1=a0, a2=a0, a3=a0;
  #pragma unroll 2
  for(int ll=0; ll<64; ll++){
    float bnd = Bd[ll][n];
    const float* xp = &Xs[ll][p0];
    a0 += bnd * *(const f32x4*)(xp);
    a1 += bnd * *(const f32x4*)(xp+4);
    a2 += bnd * *(const f32x4*)(xp+8);
    a3 += bnd * *(const f32x4*)(xp+12);
  }
  float* op = S + ((size_t)(bc*NH + h))*4096 + n*64 + p0;
  *(f32x4*)(op)    = a0;
  *(f32x4*)(op+4)  = a1;
  *(f32x4*)(op+8)  = a2;
  *(f32x4*)(op+12) = a3;
}

// ---------------- Phase B: inter-chunk scan (prev in-place) ----------------
__global__ void k_scan(float* __restrict__ S, const float* __restrict__ cdec){
  int g = blockIdx.x*256 + threadIdx.x;  // BATCH*NH*4096
  int bh = g >> 12;
  int pn = g & 4095;
  int b = bh >> 4, h = bh & 15;
  const float* cd = cdec + bh*64;
  float s = 0.f;
  for(int c=0;c<64;c++){
    size_t idx = ((size_t)((b*64 + c)*NH + h))*4096 + pn;
    float v = S[idx];
    float d = cd[c];
    S[idx] = s;
    s = s*d + v;
  }
}

// ---------------- Phase C: Y written in-place over prev slot ----------------
__global__ __launch_bounds__(256)
void k_y(const float* __restrict__ xbc, const float* __restrict__ bcc,
         const float* __restrict__ dtp, const float* __restrict__ acum,
         const float* __restrict__ cw, const float* __restrict__ cb,
         const float* __restrict__ Dp, float* __restrict__ Sreg){
  int h = blockIdx.x, bc = blockIdx.y;
  int b = bc >> 6, c = bc & 63;
  __shared__ float Cs[64][68];
  __shared__ float BM[64][68];         // B, then overwritten with M
  __shared__ float Xr[64][68];
  __shared__ float PsRaw[64*68];       // raw x [67*64], then Ps [s*68+p]
  __shared__ f32x4 wc4[64];
  __shared__ float cbv[64], acs[64], dts[64];
  int t = threadIdx.x;
  float* Sslot = Sreg + ((size_t)(bc*NH + h))*4096;
  if(t < 64){
    acs[t] = acum[((size_t)(b*NH+h))*SEQL + c*64 + t];
    dts[t] = dtp[(size_t)(b*SEQL + c*64 + t)*NH + h];
    wc4[t] = *(const f32x4*)(cw + (size_t)(h*HD + t)*4);
    cbv[t] = cb[h*HD + t];
  }
  #pragma unroll
  for(int i=0;i<4;i++){
    int idx = t + i*256;
    int l = idx>>4, n4 = (idx&15)*4;
    const float* bp = bcc + (size_t)(b*SEQL + c*64 + l)*128;
    *(f32x4*)&BM[l][n4] = *(const f32x4*)(bp + n4);       // B
    *(f32x4*)&Cs[l][n4] = *(const f32x4*)(bp + 64 + n4);  // C
  }
  #pragma unroll
  for(int i=0;i<5;i++){
    int idx = t + i*256;
    if(idx < 67*16){
      int rr = idx>>4, p4 = (idx&15)*4;
      int wb = c*64 - 3 + rr;
      f32x4 xv = {0.f,0.f,0.f,0.f};
      if(wb >= 0) xv = *(const f32x4*)(xbc + (size_t)(b*SEQL + wb)*CONVD + h*HD + p4);
      *(f32x4*)&PsRaw[rr*64 + p4] = xv;
    }
  }
  __syncthreads();
  {
    int l = t>>2, q = t&3;
    #pragma unroll
    for(int jj=0;jj<16;jj++){
      int p = q*16 + jj;
      f32x4 w = wc4[p];
      float a = cbv[p] + PsRaw[(l+0)*64+p]*w.x + PsRaw[(l+1)*64+p]*w.y
              + PsRaw[(l+2)*64+p]*w.z + PsRaw[(l+3)*64+p]*w.w;
      Xr[l][p] = silu_f(a);
    }
  }
  __syncthreads();
  int gl = t & 63, s0 = (t>>6)*16;
  float g[16];
  #pragma unroll
  for(int j=0;j<16;j++) g[j]=0.f;
  #pragma unroll 1
  for(int n4=0;n4<64;n4+=4){
    f32x4 cv = *(const f32x4*)&Cs[gl][n4];
    #pragma unroll
    for(int j=0;j<16;j++){
      f32x4 bv = *(const f32x4*)&BM[s0+j][n4];
      g[j] += cv.x*bv.x + cv.y*bv.y + cv.z*bv.z + cv.w*bv.w;
    }
  }
  __syncthreads();   // all G reads of BM done before M overwrite
  {
    float aclg = acs[gl];
    #pragma unroll
    for(int j=0;j<16;j++){
      int s = s0 + j;
      BM[gl][s] = (s <= gl) ? g[j]*__expf(aclg - acs[s])*dts[s] : 0.f;
    }
  }
  #pragma unroll
  for(int i=0;i<4;i++){
    int idx = t + i*256;
    int s = idx>>4, p4 = (idx&15)*4;
    f32x4 pv = *(const f32x4*)(Sslot + s*64 + p4);
    *(f32x4*)&PsRaw[s*68 + p4] = pv;
  }
  __syncthreads();
  {
    int l = t>>2, p0 = (t&3)*16;
    float eal = __expf(acs[l]);
    float Dh = Dp[h];
    const float* xl = &Xr[l][p0];
    f32x4 a0 = Dh * *(const f32x4*)(xl);
    f32x4 a1 = Dh * *(const f32x4*)(xl+4);
    f32x4 a2 = Dh * *(const f32x4*)(xl+8);
    f32x4 a3 = Dh * *(const f32x4*)(xl+12);
    #pragma unroll 2
    for(int s=0;s<64;s++){
      float m = BM[l][s];
      const float* xp = &Xr[s][p0];
      a0 += m * *(const f32x4*)(xp);
      a1 += m * *(const f32x4*)(xp+4);
      a2 += m * *(const f32x4*)(xp+8);
      a3 += m * *(const f32x4*)(xp+12);
    }
    #pragma unroll 2
    for(int s=0;s<64;s++){
      float cv = eal * Cs[l][s];
      const float* pp = &PsRaw[s*68 + p0];
      a0 += cv * *(const f32x4*)(pp);
      a1 += cv * *(const f32x4*)(pp+4);
      a2 += cv * *(const f32x4*)(pp+8);
      a3 += cv * *(const f32x4*)(pp+12);
    }
    float* yp = Sslot + l*64 + p0;
    *(f32x4*)(yp)    = a0;
    *(f32x4*)(yp+4)  = a1;
    *(f32x4*)(yp+8)  = a2;
    *(f32x4*)(yp+12) = a3;
  }
}

// ---------------- gate + RMSNorm -> bf16 hi/lo planes gh/gl [row][DI] ----------------
__global__ __launch_bounds__(256)
void k_gate(const float* __restrict__ Sreg, const float* __restrict__ z,
            const float* __restrict__ rms_w, unsigned short* __restrict__ gh,
            unsigned short* __restrict__ gl){
  __shared__ float sm[4];
  int row = blockIdx.x, t = threadIdx.x;
  int b = row>>12, cc = (row>>6)&63, lin = row&63;
  int h = t>>4, p = (t&15)*4;
  const float* gp = Sreg + ((size_t)((b*64+cc)*NH + h))*4096 + (size_t)lin*64 + p;
  f32x4 yv = *(const f32x4*)gp;
  f32x4 zv = *(const f32x4*)(z + (size_t)row*DI + t*4);
  f32x4 gv;
  gv.x = yv.x * silu_f(zv.x);
  gv.y = yv.y * silu_f(zv.y);
  gv.z = yv.z * silu_f(zv.z);
  gv.w = yv.w * silu_f(zv.w);
  float ss = gv.x*gv.x + gv.y*gv.y + gv.z*gv.z + gv.w*gv.w;
  for(int o=32;o;o>>=1) ss += __shfl_down(ss,o);
  if((t&63)==0) sm[t>>6] = ss;
  __syncthreads();
  float tot = sm[0]+sm[1]+sm[2]+sm[3];
  float scale = rsqrtf(tot*(1.f/DI) + 1e-5f);
  f32x4 wv = *(const f32x4*)(rms_w + t*4);
  float o0 = gv.x*scale*wv.x, o1 = gv.y*scale*wv.y;
  float o2 = gv.z*scale*wv.z, o3 = gv.w*scale*wv.w;
  u16x4 hv, lv;
  unsigned short hh;
  hh = bf16_rne(o0); hv[0]=hh; lv[0]=bf16_rne(o0-bf16_to_f(hh));
  hh = bf16_rne(o1); hv[1]=hh; lv[1]=bf16_rne(o1-bf16_to_f(hh));
  hh = bf16_rne(o2); hv[2]=hh; lv[2]=bf16_rne(o2-bf16_to_f(hh));
  hh = bf16_rne(o3); hv[3]=hh; lv[3]=bf16_rne(o3-bf16_to_f(hh));
  *(u16x4*)(gh + (size_t)row*DI + t*4) = hv;
  *(u16x4*)(gl + (size_t)row*DI + t*4) = lv;
}

extern "C" void kernel_launch(void* const* d_in, const int* in_sizes, int n_in,
                              void* d_out, int out_size, void* d_ws, size_t ws_size,
                              hipStream_t stream) {
  const float* x      = (const float*)d_in[0];
  const float* ln_w   = (const float*)d_in[1];
  const float* ln_b   = (const float*)d_in[2];
  const float* in_w   = (const float*)d_in[3];
  const float* conv_w = (const float*)d_in[4];
  const float* conv_b = (const float*)d_in[5];
  const float* dt_b   = (const float*)d_in[6];
  const float* A_log  = (const float*)d_in[7];
  const float* Dp     = (const float*)d_in[8];
  const float* rms_w  = (const float*)d_in[9];
  const float* out_w  = (const float*)d_in[10];
  float* out = (float*)d_out;
  char* ws = (char*)d_ws;

  size_t o = 0;
  float* stats = (float*)(ws+o);           o += (size_t)NROWS*2*4;        // 0.13 MB
  unsigned short* w1h = (unsigned short*)(ws+o); o += (size_t)NIP*DM*2;   // 2.23 MB
  unsigned short* w1l = (unsigned short*)(ws+o); o += (size_t)NIP*DM*2;   // 2.23 MB
  unsigned short* w2h = (unsigned short*)(ws+o); o += (size_t)DM*DI*2;    // 1.05 MB
  unsigned short* w2l = (unsigned short*)(ws+o); o += (size_t)DM*DI*2;    // 1.05 MB
  float* z    = (float*)(ws+o);            o += (size_t)NROWS*DI*4;       // 67.1 MB
  float* xbc  = (float*)(ws+o);            o += (size_t)NROWS*CONVD*4;    // 75.5 MB
  float* dtp  = (float*)(ws+o);            o += (size_t)NROWS*NH*4;       // 1.05 MB
  float* acum = (float*)(ws+o);            o += (size_t)BATCH*NH*SEQL*4;  // 1.05 MB
  float* cdec = (float*)(ws+o);            o += (size_t)BATCH*NH*64*4;    // 16 KB
  float* bcc  = (float*)(ws+o);            o += (size_t)NROWS*128*4;      // 8.39 MB
  float* Sreg = (float*)(ws+o);            o += (size_t)BATCH*64*NH*4096*4; // 67.1 MB
  if(o > ws_size) return;   // diagnostic: clean validation failure instead of OOB fault

  // Aliases (lifetime-disjoint):
  //  Ai (LN split planes, 33.6 MB) lives in Sreg region: consumed by k_gemm_in,
  //  which completes before k_states first writes Sreg.
  unsigned short* Ai = (unsigned short*)Sreg;
  //  gh/gl (gate split planes, 67.1 MB) live in xbc region: written by k_gate
  //  after the last xbc reader (k_y) is done.
  unsigned short* gh = (unsigned short*)xbc;
  unsigned short* gl = gh + (size_t)NROWS*DI;

  k_stats<<<NROWS, 256, 0, stream>>>(x, ln_w, ln_b, stats, Ai);
  k_wsplit<<<dim3(NIP/32, DM/32), dim3(32,8), 0, stream>>>(in_w,  w1h, w1l, DM, NIP, DIP);
  k_wsplit<<<dim3(DM/32,  DI/32), dim3(32,8), 0, stream>>>(out_w, w2h, w2l, DI, DM, DM);
  k_gemm_in<<<(NROWS/128)*(NIP/128), 256, 0, stream>>>(Ai, w1h, w1l, z, xbc);
  k_dt<<<NROWS, 256, 0, stream>>>(x, stats, ln_w, ln_b, in_w, dt_b, dtp);
  k_convBC<<<(NROWS*32)/256, 256, 0, stream>>>(xbc, conv_w, conv_b, bcc);
  k_acum<<<dim3(BATCH*NH, 64), 64, 0, stream>>>(dtp, A_log, acum, cdec);
  k_states<<<dim3(NH, BATCH*64), 256, 0, stream>>>(xbc, bcc, dtp, acum, conv_w, conv_b, Sreg);
  k_scan<<<(BATCH*NH*4096)/256, 256, 0, stream>>>(Sreg, cdec);
  k_y<<<dim3(NH, BATCH*64), 256, 0, stream>>>(xbc, bcc, dtp, acum, conv_w, conv_b, Dp, Sreg);
  k_gate<<<NROWS, 256, 0, stream>>>(Sreg, z, rms_w, gh, gl);
  k_gemm_out<<<(NROWS/128)*(DM/128), 256, 0, stream>>>(gh, gl, w2h, w2l, x, out);
}

// Round 8
// 657.635 us; speedup vs baseline: 3.9523x; 1.0308x over previous
//
#include <hip/hip_runtime.h>
#include <hip/hip_bf16.h>
#include <cstddef>

#define BATCH  4
#define SEQL   4096
#define DM     512
#define DIP    2192
#define NIP    2176            // in_proj cols actually needed (z + xbc)
#define DI     1024
#define DST    64
#define NH     16
#define HD     64
#define CONVD  1152
#define NROWS  (BATCH*SEQL)

typedef __attribute__((ext_vector_type(8))) short short8;
typedef __attribute__((ext_vector_type(4))) float f32x4;
typedef __attribute__((ext_vector_type(4))) unsigned short u16x4;

__device__ __forceinline__ float silu_f(float v){ return v/(1.f+__expf(-v)); }

__device__ __forceinline__ unsigned short bf16_rne(float x){
  unsigned u = __float_as_uint(x);
  unsigned r = u + 0x7FFFu + ((u>>16)&1u);
  return (unsigned short)(r>>16);
}
__device__ __forceinline__ float bf16_to_f(unsigned short h){
  return __uint_as_float(((unsigned)h)<<16);
}

// split a f32x4 into bf16 hi/lo, packed u32 stores (dst 4B-aligned)
__device__ __forceinline__ void split_pack4(f32x4 v, unsigned short* hp, unsigned short* lp){
  unsigned short h0=bf16_rne(v.x), h1=bf16_rne(v.y), h2=bf16_rne(v.z), h3=bf16_rne(v.w);
  unsigned short l0=bf16_rne(v.x-bf16_to_f(h0)), l1=bf16_rne(v.y-bf16_to_f(h1)),
                 l2=bf16_rne(v.z-bf16_to_f(h2)), l3=bf16_rne(v.w-bf16_to_f(h3));
  ((unsigned*)hp)[0] = (unsigned)h0 | ((unsigned)h1<<16);
  ((unsigned*)hp)[1] = (unsigned)h2 | ((unsigned)h3<<16);
  ((unsigned*)lp)[0] = (unsigned)l0 | ((unsigned)l1<<16);
  ((unsigned*)lp)[1] = (unsigned)l2 | ((unsigned)l3<<16);
}

// ---------------- LN stats + split-bf16 LN output planes Ai[row][2][DM] ----------------
__global__ __launch_bounds__(256)
void k_stats(const float* __restrict__ x, const float* __restrict__ lnw,
             const float* __restrict__ lnb, float* __restrict__ stats,
             unsigned short* __restrict__ Ai){
  __shared__ float sm[8];
  int row = blockIdx.x, t = threadIdx.x;
  const float* xr = x + (size_t)row*DM;
  float v0 = xr[t], v1 = xr[t+256];
  float s = v0+v1, s2 = v0*v0+v1*v1;
  for(int o=32;o;o>>=1){ s += __shfl_down(s,o); s2 += __shfl_down(s2,o); }
  if((t&63)==0){ sm[t>>6]=s; sm[4+(t>>6)]=s2; }
  __syncthreads();
  float su = sm[0]+sm[1]+sm[2]+sm[3];
  float sq = sm[4]+sm[5]+sm[6]+sm[7];
  float mu = su*(1.f/DM);
  float rs = rsqrtf(sq*(1.f/DM) - mu*mu + 1e-5f);
  if(t==0){ stats[row*2]=mu; stats[row*2+1]=rs; }
  unsigned short* ap = Ai + (size_t)row*2*DM;
  float a0 = (v0-mu)*rs*lnw[t] + lnb[t];
  unsigned short h0 = bf16_rne(a0);
  ap[t] = h0; ap[DM+t] = bf16_rne(a0 - bf16_to_f(h0));
  float a1 = (v1-mu)*rs*lnw[t+256] + lnb[t+256];
  unsigned short h1 = bf16_rne(a1);
  ap[t+256] = h1; ap[DM+t+256] = bf16_rne(a1 - bf16_to_f(h1));
}

// ------- transpose + split fp32 src[K][srcStride] (cols 0..N-1) -> bf16 hi/lo [N][K] -------
__global__ void k_wsplit(const float* __restrict__ src, unsigned short* __restrict__ dh,
                         unsigned short* __restrict__ dl, int K, int N, int srcStride){
  __shared__ float sm[32][33];
  int tx = threadIdx.x, ty = threadIdx.y;     // (32,8)
  int n0 = blockIdx.x*32, k0 = blockIdx.y*32;
  #pragma unroll
  for(int j=0;j<4;j++){
    int k = k0+ty+j*8, n = n0+tx;
    sm[ty+j*8][tx] = (k<K && n<N) ? src[(size_t)k*srcStride+n] : 0.f;
  }
  __syncthreads();
  #pragma unroll
  for(int j=0;j<4;j++){
    int n = n0+ty+j*8, k = k0+tx;
    if(n < N){
      float v = sm[tx][ty+j*8];
      unsigned short hh = bf16_rne(v);
      dh[(size_t)n*K+k] = hh;
      dl[(size_t)n*K+k] = bf16_rne(v - bf16_to_f(hh));
    }
  }
}

// ---- in_proj GEMM: Ai(hi/lo bf16) @ w1, 3-MFMA split, epilogue scatters z/xbc ----
__global__ __launch_bounds__(256)
void k_gemm_in(const unsigned short* __restrict__ Ai,
               const unsigned short* __restrict__ Bhg, const unsigned short* __restrict__ Blg,
               float* __restrict__ z, float* __restrict__ xbc){
  __shared__ unsigned short Ah[128][76], Al[128][76], Bh[128][76], Bl[128][76];
  const int ntn = NIP/128;                     // 17
  int nwg = gridDim.x;
  int bid0 = blockIdx.x;
  int bid = (bid0 & 7)*(nwg>>3) + (bid0>>3);   // XCD swizzle (nwg%8==0)
  int tm = bid / ntn, tn = bid % ntn;
  int t = threadIdx.x, lane = t&63, wave = t>>6;
  int wr = (wave>>1)*64, wc = (wave&1)*64, fr = lane&15;
  f32x4 zero = {0.f,0.f,0.f,0.f};
  f32x4 acc[4][4];
  #pragma unroll
  for(int m=0;m<4;m++)
    #pragma unroll
    for(int n=0;n<4;n++) acc[m][n]=zero;
  const int arow = tm*128, bcol = tn*128;
  int plane = (t>>3)&1;                        // uniform per thread across i
  unsigned short* Adst = plane ? &Al[0][0] : &Ah[0][0];
  for(int k0=0; k0<DM; k0+=64){
    __syncthreads();
    #pragma unroll
    for(int i=0;i<8;i++){
      int r = (t>>4) + i*16, c8 = (t&7)*8;
      *(short8*)(Adst + r*76 + c8) =
        *(const short8*)(Ai + ((size_t)(arow+r)*2 + plane)*DM + k0 + c8);
    }
    #pragma unroll
    for(int i=0;i<4;i++){
      int idx = t + i*256;
      int r = idx>>3, c8 = (idx&7)*8;
      *(short8*)(&Bh[r][c8]) = *(const short8*)(Bhg + (size_t)(bcol+r)*DM + k0 + c8);
      *(short8*)(&Bl[r][c8]) = *(const short8*)(Blg + (size_t)(bcol+r)*DM + k0 + c8);
    }
    __syncthreads();
    #pragma unroll
    for(int kk=0;kk<2;kk++){
      int fk = kk*32 + ((lane>>4)<<3);
      short8 afh[4], afl[4], bfh[4], bfl[4];
      #pragma unroll
      for(int m=0;m<4;m++){
        afh[m] = *(const short8*)(&Ah[wr+m*16+fr][fk]);
        afl[m] = *(const short8*)(&Al[wr+m*16+fr][fk]);
      }
      #pragma unroll
      for(int n=0;n<4;n++){
        bfh[n] = *(const short8*)(&Bh[wc+n*16+fr][fk]);
        bfl[n] = *(const short8*)(&Bl[wc+n*16+fr][fk]);
      }
      #pragma unroll
      for(int m=0;m<4;m++)
        #pragma unroll
        for(int n=0;n<4;n++){
          acc[m][n] = __builtin_amdgcn_mfma_f32_16x16x32_bf16(afh[m], bfh[n], acc[m][n], 0,0,0);
          acc[m][n] = __builtin_amdgcn_mfma_f32_16x16x32_bf16(afh[m], bfl[n], acc[m][n], 0,0,0);
          acc[m][n] = __builtin_amdgcn_mfma_f32_16x16x32_bf16(afl[m], bfh[n], acc[m][n], 0,0,0);
        }
    }
  }
  int fq = (lane>>4)*4;
  #pragma unroll
  for(int m=0;m<4;m++)
    #pragma unroll
    for(int n=0;n<4;n++)
      #pragma unroll
      for(int j=0;j<4;j++){
        int row = arow + wr + m*16 + fq + j;
        int col = bcol + wc + n*16 + fr;
        float v = acc[m][n][j];
        if(col < DI) z[(size_t)row*DI + col] = v;
        else xbc[(size_t)row*CONVD + (col-DI)] = v;
      }
}

// ---- out_proj GEMM: g(hi/lo bf16 row-major) @ out_w + x -> out ----
__global__ __launch_bounds__(256)
void k_gemm_out(const unsigned short* __restrict__ gh, const unsigned short* __restrict__ gl,
                const unsigned short* __restrict__ Bhg, const unsigned short* __restrict__ Blg,
                const float* __restrict__ resid, float* __restrict__ outp){
  __shared__ unsigned short Ah[128][76], Al[128][76], Bh[128][76], Bl[128][76];
  const int ntn = DM/128;                      // 4
  int nwg = gridDim.x;
  int bid0 = blockIdx.x;
  int bid = (bid0 & 7)*(nwg>>3) + (bid0>>3);
  int tm = bid / ntn, tn = bid % ntn;
  int t = threadIdx.x, lane = t&63, wave = t>>6;
  int wr = (wave>>1)*64, wc = (wave&1)*64, fr = lane&15;
  f32x4 zero = {0.f,0.f,0.f,0.f};
  f32x4 acc[4][4];
  #pragma unroll
  for(int m=0;m<4;m++)
    #pragma unroll
    for(int n=0;n<4;n++) acc[m][n]=zero;
  const int arow = tm*128, bcol = tn*128;
  int plane = (t>>3)&1;
  unsigned short* Adst = plane ? &Al[0][0] : &Ah[0][0];
  const unsigned short* gsrc = plane ? gl : gh;
  for(int k0=0; k0<DI; k0+=64){
    __syncthreads();
    #pragma unroll
    for(int i=0;i<8;i++){
      int r = (t>>4) + i*16, c8 = (t&7)*8;
      *(short8*)(Adst + r*76 + c8) =
        *(const short8*)(gsrc + (size_t)(arow+r)*DI + k0 + c8);
    }
    #pragma unroll
    for(int i=0;i<4;i++){
      int idx = t + i*256;
      int r = idx>>3, c8 = (idx&7)*8;
      *(short8*)(&Bh[r][c8]) = *(const short8*)(Bhg + (size_t)(bcol+r)*DI + k0 + c8);
      *(short8*)(&Bl[r][c8]) = *(const short8*)(Blg + (size_t)(bcol+r)*DI + k0 + c8);
    }
    __syncthreads();
    #pragma unroll
    for(int kk=0;kk<2;kk++){
      int fk = kk*32 + ((lane>>4)<<3);
      short8 afh[4], afl[4], bfh[4], bfl[4];
      #pragma unroll
      for(int m=0;m<4;m++){
        afh[m] = *(const short8*)(&Ah[wr+m*16+fr][fk]);
        afl[m] = *(const short8*)(&Al[wr+m*16+fr][fk]);
      }
      #pragma unroll
      for(int n=0;n<4;n++){
        bfh[n] = *(const short8*)(&Bh[wc+n*16+fr][fk]);
        bfl[n] = *(const short8*)(&Bl[wc+n*16+fr][fk]);
      }
      #pragma unroll
      for(int m=0;m<4;m++)
        #pragma unroll
        for(int n=0;n<4;n++){
          acc[m][n] = __builtin_amdgcn_mfma_f32_16x16x32_bf16(afh[m], bfh[n], acc[m][n], 0,0,0);
          acc[m][n] = __builtin_amdgcn_mfma_f32_16x16x32_bf16(afh[m], bfl[n], acc[m][n], 0,0,0);
          acc[m][n] = __builtin_amdgcn_mfma_f32_16x16x32_bf16(afl[m], bfh[n], acc[m][n], 0,0,0);
        }
    }
  }
  int fq = (lane>>4)*4;
  #pragma unroll
  for(int m=0;m<4;m++)
    #pragma unroll
    for(int n=0;n<4;n++)
      #pragma unroll
      for(int j=0;j<4;j++){
        int row = arow + wr + m*16 + fq + j;
        int col = bcol + wc + n*16 + fr;
        outp[(size_t)row*DM + col] = acc[m][n][j] + resid[(size_t)row*DM + col];
      }
}

// ---------------- exact fp32 dt ----------------
__global__ __launch_bounds__(256)
void k_dt(const float* __restrict__ x, const float* __restrict__ stats,
          const float* __restrict__ lnw, const float* __restrict__ lnb,
          const float* __restrict__ in_w, const float* __restrict__ dt_bias,
          float* __restrict__ dtp){
  __shared__ float red[64];
  int row = blockIdx.x, t = threadIdx.x;
  float mu = stats[row*2], rs = stats[row*2+1];
  float a[16];
  #pragma unroll
  for(int j=0;j<16;j++) a[j]=0.f;
  #pragma unroll
  for(int i=0;i<2;i++){
    int k = t + i*256;
    float hv = (x[(size_t)row*DM + k]-mu)*rs*lnw[k] + lnb[k];
    const float* wr2 = in_w + (size_t)k*DIP + (DIP-NH);
    #pragma unroll
    for(int j=0;j<16;j++) a[j] += hv * wr2[j];
  }
  for(int o=32;o;o>>=1){
    #pragma unroll
    for(int j=0;j<16;j++) a[j] += __shfl_down(a[j],o);
  }
  if((t&63)==0){
    #pragma unroll
    for(int j=0;j<16;j++) red[(t>>6)*16+j] = a[j];
  }
  __syncthreads();
  if(t<16){
    float v = red[t] + red[16+t] + red[32+t] + red[48+t] + dt_bias[t];
    dtp[(size_t)row*NH + t] = (v > 20.f) ? v : log1pf(__expf(v));
  }
}

// ---------------- conv+silu for B/C channels only -> bcc[row][128] ----------------
__global__ __launch_bounds__(256)
void k_convBC(const float* __restrict__ xbc, const float* __restrict__ cw,
              const float* __restrict__ cb, float* __restrict__ bcc){
  int gid = blockIdx.x*256 + threadIdx.x;     // NROWS*32
  int c4 = gid & 31, row = gid >> 5;
  int c = c4*4;                                // channel 1024+c .. +3
  int lb = row & (SEQL-1);
  const float* base = xbc + (size_t)row*CONVD + DI + c;
  f32x4 w0 = *(const f32x4*)(cw + (size_t)(DI+c+0)*4);
  f32x4 w1 = *(const f32x4*)(cw + (size_t)(DI+c+1)*4);
  f32x4 w2 = *(const f32x4*)(cw + (size_t)(DI+c+2)*4);
  f32x4 w3 = *(const f32x4*)(cw + (size_t)(DI+c+3)*4);
  f32x4 r = { cb[DI+c], cb[DI+c+1], cb[DI+c+2], cb[DI+c+3] };
  #pragma unroll
  for(int k=0;k<4;k++){
    if(lb-3+k >= 0){
      f32x4 xv = *(const f32x4*)(base + (long)(k-3)*CONVD);
      r.x += xv.x*w0[k]; r.y += xv.y*w1[k]; r.z += xv.z*w2[k]; r.w += xv.w*w3[k];
    }
  }
  r.x = silu_f(r.x); r.y = silu_f(r.y); r.z = silu_f(r.z); r.w = silu_f(r.w);
  *(f32x4*)(bcc + (size_t)row*128 + c) = r;
}

// ---------------- per-chunk cumsum of dt*A ----------------
__global__ void k_acum(const float* __restrict__ dtp, const float* __restrict__ A_log,
                       float* __restrict__ acum, float* __restrict__ cdec){
  int bh = blockIdx.x;                 // b*16+h
  int h = bh & 15;
  int c = blockIdx.y, l = threadIdx.x; // 64 threads
  int row = (bh>>4)*SEQL + c*64 + l;
  float a = -__expf(A_log[h]);
  float v = dtp[(size_t)row*NH + h] * a;
  for(int o=1;o<64;o<<=1){ float u = __shfl_up(v,o); if(l>=o) v += u; }
  acum[(size_t)bh*SEQL + c*64 + l] = v;
  if(l==63) cdec[bh*64 + c] = __expf(v);
}

// ---------------- Phase A: chunk states (conv-recompute for x-head) ----------------
__global__ __launch_bounds__(256)
void k_states(const float* __restrict__ xbc, const float* __restrict__ bcc,
              const float* __restrict__ dtp, const float* __restrict__ acum,
              const float* __restrict__ cw, const float* __restrict__ cb,
              float* __restrict__ S){
  int h = blockIdx.x, bc = blockIdx.y;
  int b = bc >> 6, c = bc & 63;
  __shared__ float Bd[64][68];
  __shared__ float Xs[64][68];
  __shared__ float raw[67*64];
  __shared__ f32x4 wc4[64];
  __shared__ float cbv[64], acs[64], dts[64];
  int t = threadIdx.x;
  if(t < 64){
    acs[t] = acum[((size_t)(b*NH+h))*SEQL + c*64 + t];
    dts[t] = dtp[(size_t)(b*SEQL + c*64 + t)*NH + h];
    wc4[t] = *(const f32x4*)(cw + (size_t)(h*HD + t)*4);
    cbv[t] = cb[h*HD + t];
  }
  __syncthreads();
  #pragma unroll
  for(int i=0;i<4;i++){
    int idx = t + i*256;
    int l = idx>>4, n4 = (idx&15)*4;
    f32x4 bv = *(const f32x4*)(bcc + (size_t)(b*SEQL + c*64 + l)*128 + n4);
    float dec = __expf(acs[63] - acs[l]);
    *(f32x4*)&Bd[l][n4] = bv * dec;
  }
  #pragma unroll
  for(int i=0;i<5;i++){
    int idx = t + i*256;
    if(idx < 67*16){
      int rr = idx>>4, p4 = (idx&15)*4;
      int wb = c*64 - 3 + rr;
      f32x4 xv = {0.f,0.f,0.f,0.f};
      if(wb >= 0) xv = *(const f32x4*)(xbc + (size_t)(b*SEQL + wb)*CONVD + h*HD + p4);
      *(f32x4*)&raw[rr*64 + p4] = xv;
    }
  }
  __syncthreads();
  {
    int l = t>>2, q = t&3;
    float dtv = dts[l];
    #pragma unroll
    for(int jj=0;jj<16;jj++){
      int p = q*16 + jj;
      f32x4 w = wc4[p];
      float a = cbv[p] + raw[(l+0)*64+p]*w.x + raw[(l+1)*64+p]*w.y
              + raw[(l+2)*64+p]*w.z + raw[(l+3)*64+p]*w.w;
      Xs[l][p] = silu_f(a) * dtv;
    }
  }
  __syncthreads();
  int n = t>>2, p0 = (t&3)*16;
  f32x4 a0={0.f,0.f,0.f,0.f}, a1=a0, a2=a0, a3=a0;
  #pragma unroll 2
  for(int ll=0; ll<64; ll++){
    float bnd = Bd[ll][n];
    const float* xp = &Xs[ll][p0];
    a0 += bnd * *(const f32x4*)(xp);
    a1 += bnd * *(const f32x4*)(xp+4);
    a2 += bnd * *(const f32x4*)(xp+8);
    a3 += bnd * *(const f32x4*)(xp+12);
  }
  float* op = S + ((size_t)(bc*NH + h))*4096 + n*64 + p0;
  *(f32x4*)(op)    = a0;
  *(f32x4*)(op+4)  = a1;
  *(f32x4*)(op+8)  = a2;
  *(f32x4*)(op+12) = a3;
}

// ---------------- Phase B: inter-chunk scan (prev in-place) ----------------
__global__ void k_scan(float* __restrict__ S, const float* __restrict__ cdec){
  int g = blockIdx.x*256 + threadIdx.x;  // BATCH*NH*4096
  int bh = g >> 12;
  int pn = g & 4095;
  int b = bh >> 4, h = bh & 15;
  const float* cd = cdec + bh*64;
  float s = 0.f;
  for(int c=0;c<64;c++){
    size_t idx = ((size_t)((b*64 + c)*NH + h))*4096 + pn;
    float v = S[idx];
    float d = cd[c];
    S[idx] = s;
    s = s*d + v;
  }
}

// ---------------- Phase C: Y via split-bf16 MFMA (G, Y_diag, Y_off) ----------------
// r7 showed k_y LDS-throughput-bound (193us, MfmaUtil 0). The three 64x64x64
// matmuls now run on matrix cores with hi/lo-split operands (error ~= fp32: bf16
// products are exact in fp32; only the lo*lo term ~2^-18 rel is dropped).
__global__ __launch_bounds__(256)
void k_y(const float* __restrict__ xbc, const float* __restrict__ bcc,
         const float* __restrict__ dtp, const float* __restrict__ acum,
         const float* __restrict__ cw, const float* __restrict__ cb,
         const float* __restrict__ Dp, float* __restrict__ Sreg){
  int h = blockIdx.x, bc = blockIdx.y;
  int b = bc >> 6, c = bc & 63;
  __shared__ unsigned short Bh[64][76], Bl[64][76];     // B  [s][n]
  __shared__ unsigned short Ch[64][76], Cl[64][76];     // C  [l][n]
  __shared__ unsigned short Xth[64][76], Xtl[64][76];   // Xr^T [p][s]
  __shared__ unsigned short Pth[64][76], Ptl[64][76];   // Ps^T [p][n]
  __shared__ float Mbuf[64*76];                         // raw conv input, then Mh/Ml
  __shared__ float wt[4][68];                           // conv taps transposed [k][p]
  __shared__ float acs[64], dts[64], eals[64], cbt[64];
  unsigned short* Mh = (unsigned short*)Mbuf;           // M [l][s] hi
  unsigned short* Ml = Mh + 64*76;                      // M [l][s] lo
  float* raw = Mbuf;                                    // raw[rr*68+p], 67 rows

  int t = threadIdx.x, lane = t&63, wave = t>>6;
  int fr = lane & 15, hi = lane >> 4, fq = hi*4, wr = wave*16;
  float* Sslot = Sreg + ((size_t)(bc*NH + h))*4096;

  // ---- stage scalars ----
  if(t < 64){
    float av = acum[((size_t)(b*NH+h))*SEQL + c*64 + t];
    acs[t] = av;
    eals[t] = __expf(av);
    dts[t] = dtp[(size_t)(b*SEQL + c*64 + t)*NH + h];
    f32x4 w = *(const f32x4*)(cw + (size_t)(h*HD + t)*4);
    wt[0][t] = w.x; wt[1][t] = w.y; wt[2][t] = w.z; wt[3][t] = w.w;
    cbt[t] = cb[h*HD + t];
  }
  // ---- stage B, C (split) ----
  #pragma unroll
  for(int i=0;i<4;i++){
    int idx = t + i*256;
    int l = idx>>4, n4 = (idx&15)*4;
    const float* bp = bcc + (size_t)(b*SEQL + c*64 + l)*128;
    split_pack4(*(const f32x4*)(bp + n4),      &Bh[l][n4], &Bl[l][n4]);
    split_pack4(*(const f32x4*)(bp + 64 + n4), &Ch[l][n4], &Cl[l][n4]);
  }
  // ---- stage raw conv input (fp32, aliased over M) ----
  #pragma unroll
  for(int i=0;i<5;i++){
    int idx = t + i*256;
    if(idx < 67*16){
      int rr = idx>>4, p4 = (idx&15)*4;
      int wb = c*64 - 3 + rr;
      f32x4 xv = {0.f,0.f,0.f,0.f};
      if(wb >= 0) xv = *(const f32x4*)(xbc + (size_t)(b*SEQL + wb)*CONVD + h*HD + p4);
      *(f32x4*)&raw[rr*68 + p4] = xv;
    }
  }
  // ---- stage Ps transposed (split) ----
  #pragma unroll
  for(int i=0;i<4;i++){
    int idx = t + i*256;
    int n = idx>>4, p4 = (idx&15)*4;
    f32x4 pv = *(const f32x4*)(Sslot + n*64 + p4);
    #pragma unroll
    for(int k=0;k<4;k++){
      float v = pv[k];
      unsigned short hh = bf16_rne(v);
      Pth[p4+k][n] = hh;
      Ptl[p4+k][n] = bf16_rne(v - bf16_to_f(hh));
    }
  }
  __syncthreads();

  // ---- conv + silu -> Xt (transposed, split) ----
  {
    int l = t>>2, p0 = (t&3)*16;
    f32x4 a0 = *(const f32x4*)&cbt[p0];
    f32x4 a1 = *(const f32x4*)&cbt[p0+4];
    f32x4 a2 = *(const f32x4*)&cbt[p0+8];
    f32x4 a3 = *(const f32x4*)&cbt[p0+12];
    #pragma unroll
    for(int k=0;k<4;k++){
      const float* rrow = &raw[(l+k)*68];
      const float* wrow = &wt[k][0];
      a0 += *(const f32x4*)(rrow+p0)    * *(const f32x4*)(wrow+p0);
      a1 += *(const f32x4*)(rrow+p0+4)  * *(const f32x4*)(wrow+p0+4);
      a2 += *(const f32x4*)(rrow+p0+8)  * *(const f32x4*)(wrow+p0+8);
      a3 += *(const f32x4*)(rrow+p0+12) * *(const f32x4*)(wrow+p0+12);
    }
    f32x4 av[4] = {a0,a1,a2,a3};
    #pragma unroll
    for(int pe=0;pe<4;pe++)
      #pragma unroll
      for(int e=0;e<4;e++){
        int p = p0 + pe*4 + e;
        float xv = silu_f(av[pe][e]);
        unsigned short hh = bf16_rne(xv);
        Xth[p][l] = hh;
        Xtl[p][l] = bf16_rne(xv - bf16_to_f(hh));
      }
  }
  __syncthreads();   // raw dead; Xt ready; M region now writable

  // cache this wave's C fragments (rows wr..wr+15) — A-operand for G and Y_off
  short8 cfh[2], cfl[2];
  #pragma unroll
  for(int kk=0;kk<2;kk++){
    int fk = kk*32 + hi*8;
    cfh[kk] = *(const short8*)&Ch[wr+fr][fk];
    cfl[kk] = *(const short8*)&Cl[wr+fr][fk];
  }
  // ---- G = C @ B^T -> M (masked, exp-scaled, *dt) ----
  #pragma unroll 1
  for(int sc=0; sc<4; ++sc){
    f32x4 acc = {0.f,0.f,0.f,0.f};
    #pragma unroll
    for(int kk=0;kk<2;kk++){
      int fk = kk*32 + hi*8;
      short8 bh8 = *(const short8*)&Bh[sc*16+fr][fk];
      short8 bl8 = *(const short8*)&Bl[sc*16+fr][fk];
      acc = __builtin_amdgcn_mfma_f32_16x16x32_bf16(cfh[kk], bh8, acc, 0,0,0);
      acc = __builtin_amdgcn_mfma_f32_16x16x32_bf16(cfh[kk], bl8, acc, 0,0,0);
      acc = __builtin_amdgcn_mfma_f32_16x16x32_bf16(cfl[kk], bh8, acc, 0,0,0);
    }
    int s = sc*16 + fr;
    float as_ = acs[s], ds_ = dts[s];
    #pragma unroll
    for(int j=0;j<4;j++){
      int l = wr + fq + j;
      float m = (s <= l) ? acc[j]*__expf(acs[l] - as_)*ds_ : 0.f;
      unsigned short hh = bf16_rne(m);
      Mh[l*76 + s] = hh;
      Ml[l*76 + s] = bf16_rne(m - bf16_to_f(hh));
    }
  }
  __syncthreads();

  // ---- Y = M @ Xr + diag(eal)*(C @ Ps) + D*Xr ----
  float Dh = Dp[h];
  #pragma unroll 1
  for(int pc=0; pc<4; ++pc){
    f32x4 aD = {0.f,0.f,0.f,0.f}, aO = {0.f,0.f,0.f,0.f};
    #pragma unroll
    for(int kk=0;kk<2;kk++){
      int fk = kk*32 + hi*8;
      short8 mh8 = *(const short8*)(Mh + (wr+fr)*76 + fk);
      short8 ml8 = *(const short8*)(Ml + (wr+fr)*76 + fk);
      short8 xh8 = *(const short8*)&Xth[pc*16+fr][fk];
      short8 xl8 = *(const short8*)&Xtl[pc*16+fr][fk];
      aD = __builtin_amdgcn_mfma_f32_16x16x32_bf16(mh8, xh8, aD, 0,0,0);
      aD = __builtin_amdgcn_mfma_f32_16x16x32_bf16(mh8, xl8, aD, 0,0,0);
      aD = __builtin_amdgcn_mfma_f32_16x16x32_bf16(ml8, xh8, aD, 0,0,0);
      short8 ph8 = *(const short8*)&Pth[pc*16+fr][fk];
      short8 pl8 = *(const short8*)&Ptl[pc*16+fr][fk];
      aO = __builtin_amdgcn_mfma_f32_16x16x32_bf16(cfh[kk], ph8, aO, 0,0,0);
      aO = __builtin_amdgcn_mfma_f32_16x16x32_bf16(cfh[kk], pl8, aO, 0,0,0);
      aO = __builtin_amdgcn_mfma_f32_16x16x32_bf16(cfl[kk], ph8, aO, 0,0,0);
    }
    int p = pc*16 + fr;
    #pragma unroll
    for(int j=0;j<4;j++){
      int l = wr + fq + j;
      float xr = bf16_to_f(Xth[p][l]) + bf16_to_f(Xtl[p][l]);
      Sslot[l*64 + p] = aD[j] + eals[l]*aO[j] + Dh*xr;
    }
  }
}

// ---------------- gate + RMSNorm -> bf16 hi/lo planes gh/gl [row][DI] ----------------
__global__ __launch_bounds__(256)
void k_gate(const float* __restrict__ Sreg, const float* __restrict__ z,
            const float* __restrict__ rms_w, unsigned short* __restrict__ gh,
            unsigned short* __restrict__ gl){
  __shared__ float sm[4];
  int row = blockIdx.x, t = threadIdx.x;
  int b = row>>12, cc = (row>>6)&63, lin = row&63;
  int h = t>>4, p = (t&15)*4;
  const float* gp = Sreg + ((size_t)((b*64+cc)*NH + h))*4096 + (size_t)lin*64 + p;
  f32x4 yv = *(const f32x4*)gp;
  f32x4 zv = *(const f32x4*)(z + (size_t)row*DI + t*4);
  f32x4 gv;
  gv.x = yv.x * silu_f(zv.x);
  gv.y = yv.y * silu_f(zv.y);
  gv.z = yv.z * silu_f(zv.z);
  gv.w = yv.w * silu_f(zv.w);
  float ss = gv.x*gv.x + gv.y*gv.y + gv.z*gv.z + gv.w*gv.w;
  for(int o=32;o;o>>=1) ss += __shfl_down(ss,o);
  if((t&63)==0) sm[t>>6] = ss;
  __syncthreads();
  float tot = sm[0]+sm[1]+sm[2]+sm[3];
  float scale = rsqrtf(tot*(1.f/DI) + 1e-5f);
  f32x4 wv = *(const f32x4*)(rms_w + t*4);
  float o0 = gv.x*scale*wv.x, o1 = gv.y*scale*wv.y;
  float o2 = gv.z*scale*wv.z, o3 = gv.w*scale*wv.w;
  u16x4 hv, lv;
  unsigned short hh;
  hh = bf16_rne(o0); hv[0]=hh; lv[0]=bf16_rne(o0-bf16_to_f(hh));
  hh = bf16_rne(o1); hv[1]=hh; lv[1]=bf16_rne(o1-bf16_to_f(hh));
  hh = bf16_rne(o2); hv[2]=hh; lv[2]=bf16_rne(o2-bf16_to_f(hh));
  hh = bf16_rne(o3); hv[3]=hh; lv[3]=bf16_rne(o3-bf16_to_f(hh));
  *(u16x4*)(gh + (size_t)row*DI + t*4) = hv;
  *(u16x4*)(gl + (size_t)row*DI + t*4) = lv;
}

extern "C" void kernel_launch(void* const* d_in, const int* in_sizes, int n_in,
                              void* d_out, int out_size, void* d_ws, size_t ws_size,
                              hipStream_t stream) {
  const float* x      = (const float*)d_in[0];
  const float* ln_w   = (const float*)d_in[1];
  const float* ln_b   = (const float*)d_in[2];
  const float* in_w   = (const float*)d_in[3];
  const float* conv_w = (const float*)d_in[4];
  const float* conv_b = (const float*)d_in[5];
  const float* dt_b   = (const float*)d_in[6];
  const float* A_log  = (const float*)d_in[7];
  const float* Dp     = (const float*)d_in[8];
  const float* rms_w  = (const float*)d_in[9];
  const float* out_w  = (const float*)d_in[10];
  float* out = (float*)d_out;
  char* ws = (char*)d_ws;

  size_t o = 0;
  float* stats = (float*)(ws+o);           o += (size_t)NROWS*2*4;        // 0.13 MB
  unsigned short* w1h = (unsigned short*)(ws+o); o += (size_t)NIP*DM*2;   // 2.23 MB
  unsigned short* w1l = (unsigned short*)(ws+o); o += (size_t)NIP*DM*2;   // 2.23 MB
  unsigned short* w2h = (unsigned short*)(ws+o); o += (size_t)DM*DI*2;    // 1.05 MB
  unsigned short* w2l = (unsigned short*)(ws+o); o += (size_t)DM*DI*2;    // 1.05 MB
  float* z    = (float*)(ws+o);            o += (size_t)NROWS*DI*4;       // 67.1 MB
  float* xbc  = (float*)(ws+o);            o += (size_t)NROWS*CONVD*4;    // 75.5 MB
  float* dtp  = (float*)(ws+o);            o += (size_t)NROWS*NH*4;       // 1.05 MB
  float* acum = (float*)(ws+o);            o += (size_t)BATCH*NH*SEQL*4;  // 1.05 MB
  float* cdec = (float*)(ws+o);            o += (size_t)BATCH*NH*64*4;    // 16 KB
  float* bcc  = (float*)(ws+o);            o += (size_t)NROWS*128*4;      // 8.39 MB
  float* Sreg = (float*)(ws+o);            o += (size_t)BATCH*64*NH*4096*4; // 67.1 MB
  if(o > ws_size) return;   // diagnostic: clean validation failure instead of OOB fault

  // Aliases (lifetime-disjoint):
  unsigned short* Ai = (unsigned short*)Sreg;            // LN planes, dead before k_states
  unsigned short* gh = (unsigned short*)xbc;             // gate planes, written after k_y
  unsigned short* gl = gh + (size_t)NROWS*DI;

  k_stats<<<NROWS, 256, 0, stream>>>(x, ln_w, ln_b, stats, Ai);
  k_wsplit<<<dim3(NIP/32, DM/32), dim3(32,8), 0, stream>>>(in_w,  w1h, w1l, DM, NIP, DIP);
  k_wsplit<<<dim3(DM/32,  DI/32), dim3(32,8), 0, stream>>>(out_w, w2h, w2l, DI, DM, DM);
  k_gemm_in<<<(NROWS/128)*(NIP/128), 256, 0, stream>>>(Ai, w1h, w1l, z, xbc);
  k_dt<<<NROWS, 256, 0, stream>>>(x, stats, ln_w, ln_b, in_w, dt_b, dtp);
  k_convBC<<<(NROWS*32)/256, 256, 0, stream>>>(xbc, conv_w, conv_b, bcc);
  k_acum<<<dim3(BATCH*NH, 64), 64, 0, stream>>>(dtp, A_log, acum, cdec);
  k_states<<<dim3(NH, BATCH*64), 256, 0, stream>>>(xbc, bcc, dtp, acum, conv_w, conv_b, Sreg);
  k_scan<<<(BATCH*NH*4096)/256, 256, 0, stream>>>(Sreg, cdec);
  k_y<<<dim3(NH, BATCH*64), 256, 0, stream>>>(xbc, bcc, dtp, acum, conv_w, conv_b, Dp, Sreg);
  k_gate<<<NROWS, 256, 0, stream>>>(Sreg, z, rms_w, gh, gl);
  k_gemm_out<<<(NROWS/128)*(DM/128), 256, 0, stream>>>(gh, gl, w2h, w2l, x, out);
}